// Round 3
// baseline (237.143 us; speedup 1.0000x reference)
//
#include <hip/hip_runtime.h>
#include <math.h>

#define Ss 2048
#define Dd 1024
#define Pp 9
#define DMm 256
#define Tt 8192
#define EPSf 1e-5f
#define BAND 6e-3f       // fp64-rescue band for argmax ties (~8.5 sigma of bf16 score noise)

typedef __attribute__((ext_vector_type(8))) __bf16 bf16x8;
typedef __attribute__((ext_vector_type(4))) float f32x4;

#define GLOBAL_AS __attribute__((address_space(1)))
#define LDS_AS __attribute__((address_space(3)))

__device__ __forceinline__ unsigned short bf16rn(float f) {
  unsigned int u = __float_as_uint(f);
  unsigned int r = (u + 0x7fffu + ((u >> 16) & 1u)) >> 16;
  return (unsigned short)r;
}

__device__ __forceinline__ void gload16(const void* g, void* l) {
  __builtin_amdgcn_global_load_lds((const GLOBAL_AS unsigned int*)g,
                                   (LDS_AS unsigned int*)l, 16, 0, 0);
}

// swizzled LDS offset (in shorts) for logical (row r, k-slot ks); row stride 32 bf16
__device__ __forceinline__ int swz(int r, int ks) {
  return r * 32 + (ks ^ ((r >> 1) & 3)) * 8;
}

// ---------------------------------------------------------------- mix -> bf16
__global__ __launch_bounds__(256) void k_mix2(const float* __restrict__ x,
    const float* __restrict__ mk, unsigned short* __restrict__ xh) {
  const int t = blockIdx.x;
  const int s = t & (Ss - 1);
  const int d = threadIdx.x << 2;
  const float* xc = x + (size_t)t * Dd + d;
  float4 vb = *(const float4*)xc;
  float4 va = make_float4(0.f, 0.f, 0.f, 0.f);
  float4 vc = make_float4(0.f, 0.f, 0.f, 0.f);
  if (s > 0)      va = *(const float4*)(xc - Dd);
  if (s < Ss - 1) vc = *(const float4*)(xc + Dd);
  const float4 k0 = *(const float4*)(mk + d);
  const float4 k1 = *(const float4*)(mk + Dd + d);
  const float4 k2 = *(const float4*)(mk + 2 * Dd + d);
  float4 o;
  o.x = k0.x * va.x + k1.x * vb.x + k2.x * vc.x;
  o.y = k0.y * va.y + k1.y * vb.y + k2.y * vc.y;
  o.z = k0.z * va.z + k1.z * vb.z + k2.z * vc.z;
  o.w = k0.w * va.w + k1.w * vb.w + k2.w * vc.w;
  ushort4 h;
  h.x = bf16rn(o.x); h.y = bf16rn(o.y); h.z = bf16rn(o.z); h.w = bf16rn(o.w);
  *(ushort4*)(xh + (size_t)t * Dd + d) = h;
}

// ---------------------------------------------------------------- convert + transpose weights to bf16 [C][R]
__global__ __launch_bounds__(256) void k_cvtT(const float* __restrict__ in,
    unsigned short* __restrict__ out, int R, int C) {
  const size_t zo = (size_t)blockIdx.z * R * C;
  __shared__ float tile[32][33];
  const int r0 = blockIdx.x * 32, c0 = blockIdx.y * 32;
  const int tr = threadIdx.x >> 3, tc = (threadIdx.x & 7) << 2;
  float4 v = *(const float4*)(in + zo + (size_t)(r0 + tr) * C + c0 + tc);
  tile[tr][tc] = v.x; tile[tr][tc + 1] = v.y; tile[tr][tc + 2] = v.z; tile[tr][tc + 3] = v.w;
  __syncthreads();
  ushort4 h;
  h.x = bf16rn(tile[tc + 0][tr]); h.y = bf16rn(tile[tc + 1][tr]);
  h.z = bf16rn(tile[tc + 2][tr]); h.w = bf16rn(tile[tc + 3][tr]);
  *(ushort4*)(out + zo + (size_t)(c0 + tr) * R + r0 + tc) = h;
}

// ---------------------------------------------------------------- MFMA GEMM, 128x64 tile, gload_lds staging
// MODE 0: outf = tanh(acc+bias) (dense)   MODE 1: outh = bf16(acc+bias) (grouped)
// MODE 2: outf = acc+bias+resid (grouped)
template<int KTOT, int NTOT, int MODE>
__global__ __launch_bounds__(256) void k_gemm(
    const unsigned short* __restrict__ A,
    const unsigned short* __restrict__ Bt,
    const float* __restrict__ bias,
    const float* __restrict__ resid,
    float* __restrict__ outf, unsigned short* __restrict__ outh,
    const int* __restrict__ counts, const int* __restrict__ tokenlist) {
  const int z = blockIdx.z;
  const int cnt = counts ? counts[z] : Tt;
  const int tile0 = blockIdx.x * 128;
  if (tile0 >= cnt) return;
  __shared__ int tl[128];
  __shared__ __align__(16) unsigned short As[128 * 32];  // 8 KB, swizzled slots
  __shared__ __align__(16) unsigned short Bs[64 * 32];   // 4 KB, swizzled slots
  const int tid = threadIdx.x;
  if (tid < 128) {
    const int li = tile0 + tid;
    if (tokenlist) tl[tid] = (li < cnt) ? tokenlist[z * Tt + li] : tokenlist[z * Tt];
    else           tl[tid] = li;
  }
  __syncthreads();
  const int w = tid >> 6, lane = tid & 63;
  const int fr = lane & 15, fs = lane >> 4;
  const int n0 = blockIdx.y * 64;
  const unsigned short* Bp0 = Bt + (size_t)z * NTOT * KTOT + (size_t)n0 * KTOT;
  // staging descriptors (per-thread global slot, linear LDS dest)
  const int qa0 = tid,       ra0 = qa0 >> 2, sa0 = (qa0 & 3) ^ ((qa0 >> 3) & 3);
  const int qa1 = 256 + tid, ra1 = qa1 >> 2, sa1 = (qa1 & 3) ^ ((qa1 >> 3) & 3);
  const unsigned short* srcA0 = A + (size_t)tl[ra0] * KTOT + sa0 * 8;
  const unsigned short* srcA1 = A + (size_t)tl[ra1] * KTOT + sa1 * 8;
  const unsigned short* srcB  = Bp0 + (size_t)ra0 * KTOT + sa0 * 8;
  unsigned short* ldsA0 = As + (size_t)(w * 64) * 8;
  unsigned short* ldsA1 = As + (size_t)(256 + w * 64) * 8;
  unsigned short* ldsB  = Bs + (size_t)(w * 64) * 8;
  // frag read offsets
  const int aoff0 = swz(w * 32 + fr, fs);
  const int aoff1 = swz(w * 32 + 16 + fr, fs);
  const int boff0 = swz(fr, fs);
  const int boff1 = swz(16 + fr, fs);
  const int boff2 = swz(32 + fr, fs);
  const int boff3 = swz(48 + fr, fs);
  f32x4 acc[2][4] = {};
  for (int kb = 0; kb < KTOT; kb += 32) {
    gload16(srcA0 + kb, ldsA0);
    gload16(srcA1 + kb, ldsA1);
    gload16(srcB + kb, ldsB);
    __syncthreads();
    const bf16x8 a0 = *(const bf16x8*)&As[aoff0];
    const bf16x8 a1 = *(const bf16x8*)&As[aoff1];
    const bf16x8 b0 = *(const bf16x8*)&Bs[boff0];
    const bf16x8 b1 = *(const bf16x8*)&Bs[boff1];
    const bf16x8 b2 = *(const bf16x8*)&Bs[boff2];
    const bf16x8 b3 = *(const bf16x8*)&Bs[boff3];
    acc[0][0] = __builtin_amdgcn_mfma_f32_16x16x32_bf16(a0, b0, acc[0][0], 0, 0, 0);
    acc[0][1] = __builtin_amdgcn_mfma_f32_16x16x32_bf16(a0, b1, acc[0][1], 0, 0, 0);
    acc[0][2] = __builtin_amdgcn_mfma_f32_16x16x32_bf16(a0, b2, acc[0][2], 0, 0, 0);
    acc[0][3] = __builtin_amdgcn_mfma_f32_16x16x32_bf16(a0, b3, acc[0][3], 0, 0, 0);
    acc[1][0] = __builtin_amdgcn_mfma_f32_16x16x32_bf16(a1, b0, acc[1][0], 0, 0, 0);
    acc[1][1] = __builtin_amdgcn_mfma_f32_16x16x32_bf16(a1, b1, acc[1][1], 0, 0, 0);
    acc[1][2] = __builtin_amdgcn_mfma_f32_16x16x32_bf16(a1, b2, acc[1][2], 0, 0, 0);
    acc[1][3] = __builtin_amdgcn_mfma_f32_16x16x32_bf16(a1, b3, acc[1][3], 0, 0, 0);
    __syncthreads();
  }
  // C/D layout: col = fr, row = fs*4 + j (verified R2)
  const float* bias_z = bias + (size_t)z * NTOT;
  #pragma unroll
  for (int m = 0; m < 2; ++m) {
    #pragma unroll
    for (int j = 0; j < 4; ++j) {
      const int rr = w * 32 + m * 16 + fs * 4 + j;
      const int li = tile0 + rr;
      if (li >= cnt) continue;
      const int t = tl[rr];
      #pragma unroll
      for (int n = 0; n < 4; ++n) {
        const int c = n0 + n * 16 + fr;
        const float v = acc[m][n][j] + bias_z[c];
        if (MODE == 0)      outf[(size_t)t * NTOT + c] = tanhf(v);
        else if (MODE == 1) outh[(size_t)t * NTOT + c] = bf16rn(v);
        else                outf[(size_t)t * NTOT + c] = v + resid[(size_t)t * NTOT + c];
      }
    }
  }
}

// ---------------------------------------------------------------- scores + argmax + near-tie flag
__global__ __launch_bounds__(256) void k_score(const float* __restrict__ hidden,
    const float* __restrict__ Wo2, const float* __restrict__ bo2,
    int* __restrict__ idx, int* __restrict__ nflag, int* __restrict__ flagged) {
  __shared__ float sW[DMm * Pp];
  const int tid = threadIdx.x;
  for (int l = tid; l < DMm * Pp; l += 256) sW[l] = Wo2[l];
  __syncthreads();
  const int wave = tid >> 6, lane = tid & 63;
  const int t = blockIdx.x * 4 + wave;
  const float4 h = *(const float4*)(hidden + (size_t)t * DMm + lane * 4);
  const int m = lane * 4;
  float part[Pp];
  #pragma unroll
  for (int pp = 0; pp < Pp; ++pp)
    part[pp] = h.x * sW[(m + 0) * Pp + pp] + h.y * sW[(m + 1) * Pp + pp]
             + h.z * sW[(m + 2) * Pp + pp] + h.w * sW[(m + 3) * Pp + pp];
  #pragma unroll
  for (int off = 32; off > 0; off >>= 1)
    #pragma unroll
    for (int pp = 0; pp < Pp; ++pp)
      part[pp] += __shfl_xor(part[pp], off);
  if (lane == 0) {
    float best = -1e30f, second = -1e30f;
    int bi = 0;
    #pragma unroll
    for (int pp = 0; pp < Pp; ++pp) {
      const float sc = part[pp] + bo2[pp];
      if (sc > best) { second = best; best = sc; bi = pp; }
      else if (sc > second) second = sc;
    }
    idx[t] = bi;
    if (best - second < BAND) {
      const int pos = atomicAdd(nflag, 1);
      flagged[pos] = t;
    }
  }
}

// ---------------------------------------------------------------- fp64 rescue (parallelized)
__global__ __launch_bounds__(256) void k_rescue(const float* __restrict__ x,
    const float* __restrict__ mk,
    const float* __restrict__ Wo1, const float* __restrict__ bo1,
    const float* __restrict__ Wo2, const float* __restrict__ bo2,
    const int* __restrict__ nflag, const int* __restrict__ flagged,
    int* __restrict__ idx) {
  __shared__ double sx[Dd];
  __shared__ double th[DMm];
  __shared__ double red[4][12];
  const int nf = *nflag;
  const int tid = threadIdx.x;
  const int wv = tid >> 6, ln = tid & 63;
  for (int f = blockIdx.x; f < nf; f += gridDim.x) {
    const int t = flagged[f];
    const int s = t & (Ss - 1);
    for (int l = tid; l < Dd; l += 256) {
      const double xa = (s > 0)      ? (double)x[(size_t)(t - 1) * Dd + l] : 0.0;
      const double xb =                (double)x[(size_t)t * Dd + l];
      const double xc = (s < Ss - 1) ? (double)x[(size_t)(t + 1) * Dd + l] : 0.0;
      sx[l] = (double)mk[l] * xa + (double)mk[Dd + l] * xb + (double)mk[2 * Dd + l] * xc;
    }
    __syncthreads();
    {
      double a0 = 0, a1 = 0, a2 = 0, a3 = 0;
      const float* wcol = Wo1 + tid;
      for (int d = 0; d < Dd; d += 4) {
        a0 += sx[d + 0] * (double)wcol[(size_t)(d + 0) * DMm];
        a1 += sx[d + 1] * (double)wcol[(size_t)(d + 1) * DMm];
        a2 += sx[d + 2] * (double)wcol[(size_t)(d + 2) * DMm];
        a3 += sx[d + 3] * (double)wcol[(size_t)(d + 3) * DMm];
      }
      th[tid] = tanh(((a0 + a1) + (a2 + a3)) + (double)bo1[tid]);
    }
    __syncthreads();
    double pr[Pp];
    const double tv = th[tid];
    #pragma unroll
    for (int p = 0; p < Pp; ++p) pr[p] = tv * (double)Wo2[tid * Pp + p];
    #pragma unroll
    for (int off = 32; off > 0; off >>= 1)
      #pragma unroll
      for (int p = 0; p < Pp; ++p) pr[p] += __shfl_xor(pr[p], off);
    if (ln == 0) {
      #pragma unroll
      for (int p = 0; p < Pp; ++p) red[wv][p] = pr[p];
    }
    __syncthreads();
    if (tid == 0) {
      double best = -1e300; int bi = 0;
      #pragma unroll
      for (int p = 0; p < Pp; ++p) {
        const double sv = red[0][p] + red[1][p] + red[2][p] + red[3][p] + (double)bo2[p];
        if (sv > best) { best = sv; bi = p; }
      }
      idx[t] = bi;
    }
    __syncthreads();
  }
}

// ---------------------------------------------------------------- group tokens by path
__global__ __launch_bounds__(256) void k_scatter(const int* __restrict__ idx,
    int* __restrict__ counts, int* __restrict__ tokenlist) {
  const int t = blockIdx.x * 256 + threadIdx.x;
  const int p = idx[t];
  const int pos = atomicAdd(&counts[p], 1);
  tokenlist[p * Tt + pos] = t;
}

// ---------------------------------------------------------------- in-place LayerNorm
__global__ __launch_bounds__(256) void k_ln(float* __restrict__ y,
    const float* __restrict__ gamma, const float* __restrict__ beta) {
  const int t = blockIdx.x;
  const int d = threadIdx.x << 2;
  float* row = y + (size_t)t * Dd;
  float4 v = *(float4*)(row + d);
  float s = v.x + v.y + v.z + v.w;
  float q = v.x * v.x + v.y * v.y + v.z * v.z + v.w * v.w;
  #pragma unroll
  for (int off = 32; off > 0; off >>= 1) {
    s += __shfl_xor(s, off);
    q += __shfl_xor(q, off);
  }
  __shared__ float ssum[4], sqq[4];
  const int wave = threadIdx.x >> 6, lane = threadIdx.x & 63;
  if (lane == 0) { ssum[wave] = s; sqq[wave] = q; }
  __syncthreads();
  s = ssum[0] + ssum[1] + ssum[2] + ssum[3];
  q = sqq[0] + sqq[1] + sqq[2] + sqq[3];
  const float mu = s * (1.f / Dd);
  const float var = q * (1.f / Dd) - mu * mu;
  const float inv = rsqrtf(var + EPSf);
  const float4 g = *(const float4*)(gamma + d);
  const float4 bt = *(const float4*)(beta + d);
  float4 o;
  o.x = (v.x - mu) * inv * g.x + bt.x;
  o.y = (v.y - mu) * inv * g.y + bt.y;
  o.z = (v.z - mu) * inv * g.z + bt.z;
  o.w = (v.w - mu) * inv * g.w + bt.w;
  *(float4*)(row + d) = o;
}

// ----------------------------------------------------------------
extern "C" void kernel_launch(void* const* d_in, const int* in_sizes, int n_in,
                              void* d_out, int out_size, void* d_ws, size_t ws_size,
                              hipStream_t stream) {
  (void)in_sizes; (void)n_in; (void)out_size; (void)ws_size;
  const float* x     = (const float*)d_in[0];
  const float* mk    = (const float*)d_in[1];
  const float* W1    = (const float*)d_in[2];
  const float* b1    = (const float*)d_in[3];
  const float* W2    = (const float*)d_in[4];
  const float* b2    = (const float*)d_in[5];
  const float* Wo1   = (const float*)d_in[6];
  const float* bo1   = (const float*)d_in[7];
  const float* Wo2   = (const float*)d_in[8];
  const float* bo2   = (const float*)d_in[9];
  const float* gamma = (const float*)d_in[10];
  const float* beta  = (const float*)d_in[11];
  float* out = (float*)d_out;

  size_t off = 0;
  auto alloc = [&](size_t bytes) -> void* {
    void* p = (char*)d_ws + off;
    off += (bytes + 255) & ~(size_t)255;
    return p;
  };
  unsigned short* xm_h   = (unsigned short*)alloc((size_t)Tt * Dd * 2);
  float*          hidden = (float*)alloc((size_t)Tt * DMm * 4);
  unsigned short* h1     = (unsigned short*)hidden;  // alias: hidden dead before h1 written
  unsigned short* W1t    = (unsigned short*)alloc((size_t)Pp * Dd * DMm * 2);
  unsigned short* W2t    = (unsigned short*)alloc((size_t)Pp * DMm * Dd * 2);
  unsigned short* Wo1t   = (unsigned short*)alloc((size_t)Dd * DMm * 2);
  int* idx      = (int*)alloc(Tt * 4);
  int* counts   = (int*)alloc(64 * 4);
  int* nflag    = counts + 16;
  int* flagged  = (int*)alloc(Tt * 4);
  int* tokenlist = (int*)alloc((size_t)Pp * Tt * 4);

  hipMemsetAsync(counts, 0, 256, stream);

  k_mix2<<<Tt, 256, 0, stream>>>(x, mk, xm_h);
  k_cvtT<<<dim3(Dd / 32, DMm / 32, Pp), 256, 0, stream>>>(W1, W1t, Dd, DMm);
  k_cvtT<<<dim3(DMm / 32, Dd / 32, Pp), 256, 0, stream>>>(W2, W2t, DMm, Dd);
  k_cvtT<<<dim3(Dd / 32, DMm / 32, 1), 256, 0, stream>>>(Wo1, Wo1t, Dd, DMm);

  k_gemm<Dd, DMm, 0><<<dim3(Tt / 128, DMm / 64, 1), 256, 0, stream>>>(
      xm_h, Wo1t, bo1, nullptr, hidden, nullptr, nullptr, nullptr);
  k_score<<<Tt / 4, 256, 0, stream>>>(hidden, Wo2, bo2, idx, nflag, flagged);
  k_rescue<<<256, 256, 0, stream>>>(x, mk, Wo1, bo1, Wo2, bo2, nflag, flagged, idx);
  k_scatter<<<Tt / 256, 256, 0, stream>>>(idx, counts, tokenlist);

  k_gemm<Dd, DMm, 1><<<dim3(Tt / 128, DMm / 64, Pp), 256, 0, stream>>>(
      xm_h, W1t, b1, nullptr, nullptr, h1, counts, tokenlist);
  k_gemm<DMm, Dd, 2><<<dim3(Tt / 128, Dd / 64, Pp), 256, 0, stream>>>(
      h1, W2t, b2, x, out, nullptr, counts, tokenlist);
  k_ln<<<Tt, 256, 0, stream>>>(out, gamma, beta);
}

// Round 4
// 226.490 us; speedup vs baseline: 1.0470x; 1.0470x over previous
//
#include <hip/hip_runtime.h>
#include <math.h>

#define Ss 2048
#define Dd 1024
#define Pp 9
#define DMm 256
#define Tt 8192
#define EPSf 1e-5f
#define BAND 6e-3f       // fp64-rescue band for argmax ties

typedef __attribute__((ext_vector_type(8))) __bf16 bf16x8;
typedef __attribute__((ext_vector_type(4))) float f32x4;

#define GLOBAL_AS __attribute__((address_space(1)))
#define LDS_AS __attribute__((address_space(3)))

__device__ __forceinline__ unsigned short bf16rn(float f) {
  unsigned int u = __float_as_uint(f);
  unsigned int r = (u + 0x7fffu + ((u >> 16) & 1u)) >> 16;
  return (unsigned short)r;
}

__device__ __forceinline__ void gload16(const void* g, void* l) {
  __builtin_amdgcn_global_load_lds((const GLOBAL_AS unsigned int*)g,
                                   (LDS_AS unsigned int*)l, 16, 0, 0);
}

// swizzled LDS short-offset for logical (row r, 16B-slot sl); row = 64 shorts (128B)
#define KSW(r, sl) (((r) << 6) + ((((sl) ^ ((r) & 7))) << 3))

// ---------------------------------------------------------------- mix -> bf16
__global__ __launch_bounds__(256) void k_mix2(const float* __restrict__ x,
    const float* __restrict__ mk, unsigned short* __restrict__ xh) {
  const int t = blockIdx.x;
  const int s = t & (Ss - 1);
  const int d = threadIdx.x << 2;
  const float* xc = x + (size_t)t * Dd + d;
  float4 vb = *(const float4*)xc;
  float4 va = make_float4(0.f, 0.f, 0.f, 0.f);
  float4 vc = make_float4(0.f, 0.f, 0.f, 0.f);
  if (s > 0)      va = *(const float4*)(xc - Dd);
  if (s < Ss - 1) vc = *(const float4*)(xc + Dd);
  const float4 k0 = *(const float4*)(mk + d);
  const float4 k1 = *(const float4*)(mk + Dd + d);
  const float4 k2 = *(const float4*)(mk + 2 * Dd + d);
  float4 o;
  o.x = k0.x * va.x + k1.x * vb.x + k2.x * vc.x;
  o.y = k0.y * va.y + k1.y * vb.y + k2.y * vc.y;
  o.z = k0.z * va.z + k1.z * vb.z + k2.z * vc.z;
  o.w = k0.w * va.w + k1.w * vb.w + k2.w * vc.w;
  ushort4 h;
  h.x = bf16rn(o.x); h.y = bf16rn(o.y); h.z = bf16rn(o.z); h.w = bf16rn(o.w);
  *(ushort4*)(xh + (size_t)t * Dd + d) = h;
}

// ---------------------------------------------------------------- all weight converts in one launch
__global__ __launch_bounds__(256) void k_cvt_all(
    const float* __restrict__ W1, const float* __restrict__ W2,
    const float* __restrict__ Wo1,
    unsigned short* __restrict__ W1t, unsigned short* __restrict__ W2t,
    unsigned short* __restrict__ Wo1t) {
  const int z = blockIdx.z;
  const float* in; unsigned short* outp; int R, C;
  if (z < Pp)            { in = W1;  outp = W1t;  R = Dd;  C = DMm; }
  else if (z < 2 * Pp)   { in = W2;  outp = W2t;  R = DMm; C = Dd;  }
  else                   { in = Wo1; outp = Wo1t; R = Dd;  C = DMm; }
  const int zi = (z < Pp) ? z : ((z < 2 * Pp) ? z - Pp : 0);
  const int r0 = blockIdx.x * 32, c0 = blockIdx.y * 32;
  if (r0 >= R || c0 >= C) return;
  const size_t zo = (size_t)zi * R * C;
  __shared__ float tile[32][33];
  const int tr = threadIdx.x >> 3, tc = (threadIdx.x & 7) << 2;
  float4 v = *(const float4*)(in + zo + (size_t)(r0 + tr) * C + c0 + tc);
  tile[tr][tc] = v.x; tile[tr][tc + 1] = v.y; tile[tr][tc + 2] = v.z; tile[tr][tc + 3] = v.w;
  __syncthreads();
  ushort4 h;
  h.x = bf16rn(tile[tc + 0][tr]); h.y = bf16rn(tile[tc + 1][tr]);
  h.z = bf16rn(tile[tc + 2][tr]); h.w = bf16rn(tile[tc + 3][tr]);
  *(ushort4*)(outp + zo + (size_t)(c0 + tr) * R + r0 + tc) = h;
}

// ---------------------------------------------------------------- pipelined MFMA GEMM
// 128x64 tile, BK=64, dbuf LDS + counted vmcnt (T3+T4 minimum pattern)
// MODE 0: outf = tanh(acc+bias)   MODE 1: outh = bf16(acc+bias)   MODE 2: outf = acc+bias+resid
template<int KTOT, int NTOT, int MODE>
__global__ __launch_bounds__(256) void k_gemm(
    const unsigned short* __restrict__ A,
    const unsigned short* __restrict__ Bt,
    const float* __restrict__ bias,
    const float* __restrict__ resid,
    float* __restrict__ outf, unsigned short* __restrict__ outh,
    const int* __restrict__ counts, const int* __restrict__ tokenlist) {
  const int z = blockIdx.z;
  const int cnt = counts ? counts[z] : Tt;
  const int tile0 = blockIdx.x * 128;
  if (tile0 >= cnt) return;
  __shared__ int tl[128];
  __shared__ __align__(16) unsigned short As[2][128 * 64];  // 2 x 16 KB
  __shared__ __align__(16) unsigned short Bs[2][64 * 64];   // 2 x  8 KB
  const int tid = threadIdx.x;
  if (tid < 128) {
    const int li = tile0 + tid;
    if (tokenlist) tl[tid] = (li < cnt) ? tokenlist[z * Tt + li] : tokenlist[z * Tt];
    else           tl[tid] = li;
  }
  __syncthreads();
  const int w = tid >> 6, lane = tid & 63;
  const int fr = lane & 15, fs = lane >> 4;
  const int n0 = blockIdx.y * 64;
  const unsigned short* Bp0 = Bt + (size_t)z * NTOT * KTOT + (size_t)n0 * KTOT;
  // staging: unit u = load_i*256 + tid ; phys LDS slot u ; global (row u>>3, slot (u&7)^(row&7))
  const unsigned short* srcA[4];
  #pragma unroll
  for (int i = 0; i < 4; ++i) {
    const int u = i * 256 + tid, r = u >> 3, sl = (u & 7) ^ (r & 7);
    srcA[i] = A + (size_t)tl[r] * KTOT + sl * 8;
  }
  const unsigned short* srcB[2];
  #pragma unroll
  for (int i = 0; i < 2; ++i) {
    const int u = i * 256 + tid, r = u >> 3, sl = (u & 7) ^ (r & 7);
    srcB[i] = Bp0 + (size_t)r * KTOT + sl * 8;
  }
  const int ldsW = w * 512;  // wave-uniform dest (shorts): 64 lanes x 8 shorts
  // fragment read offsets (swizzled)
  int aoff[2][2], boff[4][2];
  #pragma unroll
  for (int m = 0; m < 2; ++m)
    #pragma unroll
    for (int kk = 0; kk < 2; ++kk)
      aoff[m][kk] = KSW(w * 32 + m * 16 + fr, kk * 4 + fs);
  #pragma unroll
  for (int n = 0; n < 4; ++n)
    #pragma unroll
    for (int kk = 0; kk < 2; ++kk)
      boff[n][kk] = KSW(n * 16 + fr, kk * 4 + fs);

#define STAGE(b, kb) do { \
    unsigned short* A0 = &As[b][0]; unsigned short* B0 = &Bs[b][0]; \
    gload16(srcA[0] + (kb), A0 + ldsW); \
    gload16(srcA[1] + (kb), A0 + 2048 + ldsW); \
    gload16(srcA[2] + (kb), A0 + 4096 + ldsW); \
    gload16(srcA[3] + (kb), A0 + 6144 + ldsW); \
    gload16(srcB[0] + (kb), B0 + ldsW); \
    gload16(srcB[1] + (kb), B0 + 2048 + ldsW); \
  } while (0)

  f32x4 acc[2][4] = {};
  const int NS = KTOT / 64;
  STAGE(0, 0);
  for (int s = 0; s < NS; ++s) {
    const int buf = s & 1;
    if (s + 1 < NS) {
      STAGE(buf ^ 1, (s + 1) * 64);
      asm volatile("s_waitcnt vmcnt(6)" ::: "memory");   // wait only oldest 6 (current buf)
    } else {
      asm volatile("s_waitcnt vmcnt(0)" ::: "memory");
    }
    __builtin_amdgcn_s_barrier();
    __builtin_amdgcn_sched_barrier(0);
    const unsigned short* Ab = &As[buf][0];
    const unsigned short* Bb_ = &Bs[buf][0];
    bf16x8 a[2][2], b[4][2];
    #pragma unroll
    for (int m = 0; m < 2; ++m)
      #pragma unroll
      for (int kk = 0; kk < 2; ++kk)
        a[m][kk] = *(const bf16x8*)&Ab[aoff[m][kk]];
    #pragma unroll
    for (int n = 0; n < 4; ++n)
      #pragma unroll
      for (int kk = 0; kk < 2; ++kk)
        b[n][kk] = *(const bf16x8*)&Bb_[boff[n][kk]];
    #pragma unroll
    for (int kk = 0; kk < 2; ++kk)
      #pragma unroll
      for (int m = 0; m < 2; ++m)
        #pragma unroll
        for (int n = 0; n < 4; ++n)
          acc[m][n] = __builtin_amdgcn_mfma_f32_16x16x32_bf16(a[m][kk], b[n][kk], acc[m][n], 0, 0, 0);
    __builtin_amdgcn_s_barrier();   // all reads of buf done before it is restaged
  }
#undef STAGE

  // C/D layout: col = fr, row = fs*4 + j
  const float* bias_z = bias + (size_t)z * NTOT;
  #pragma unroll
  for (int m = 0; m < 2; ++m) {
    #pragma unroll
    for (int j = 0; j < 4; ++j) {
      const int rr = w * 32 + m * 16 + fs * 4 + j;
      const int li = tile0 + rr;
      if (li >= cnt) continue;
      const int t = tl[rr];
      #pragma unroll
      for (int n = 0; n < 4; ++n) {
        const int c = n0 + n * 16 + fr;
        const float v = acc[m][n][j] + bias_z[c];
        if (MODE == 0)      outf[(size_t)t * NTOT + c] = tanhf(v);
        else if (MODE == 1) outh[(size_t)t * NTOT + c] = bf16rn(v);
        else                outf[(size_t)t * NTOT + c] = v + resid[(size_t)t * NTOT + c];
      }
    }
  }
}

// ---------------------------------------------------------------- scores + argmax + near-tie flag
__global__ __launch_bounds__(256) void k_score(const float* __restrict__ hidden,
    const float* __restrict__ Wo2, const float* __restrict__ bo2,
    int* __restrict__ idx, int* __restrict__ nflag, int* __restrict__ flagged) {
  __shared__ float sW[DMm * Pp];
  const int tid = threadIdx.x;
  for (int l = tid; l < DMm * Pp; l += 256) sW[l] = Wo2[l];
  __syncthreads();
  const int wave = tid >> 6, lane = tid & 63;
  const int t = blockIdx.x * 4 + wave;
  const float4 h = *(const float4*)(hidden + (size_t)t * DMm + lane * 4);
  const int m = lane * 4;
  float part[Pp];
  #pragma unroll
  for (int pp = 0; pp < Pp; ++pp)
    part[pp] = h.x * sW[(m + 0) * Pp + pp] + h.y * sW[(m + 1) * Pp + pp]
             + h.z * sW[(m + 2) * Pp + pp] + h.w * sW[(m + 3) * Pp + pp];
  #pragma unroll
  for (int off = 32; off > 0; off >>= 1)
    #pragma unroll
    for (int pp = 0; pp < Pp; ++pp)
      part[pp] += __shfl_xor(part[pp], off);
  if (lane == 0) {
    float best = -1e30f, second = -1e30f;
    int bi = 0;
    #pragma unroll
    for (int pp = 0; pp < Pp; ++pp) {
      const float sc = part[pp] + bo2[pp];
      if (sc > best) { second = best; best = sc; bi = pp; }
      else if (sc > second) second = sc;
    }
    idx[t] = bi;
    if (best - second < BAND) {
      const int pos = atomicAdd(nflag, 1);
      flagged[pos] = t;
    }
  }
}

// ---------------------------------------------------------------- fp64 rescue (parallelized)
__global__ __launch_bounds__(256) void k_rescue(const float* __restrict__ x,
    const float* __restrict__ mk,
    const float* __restrict__ Wo1, const float* __restrict__ bo1,
    const float* __restrict__ Wo2, const float* __restrict__ bo2,
    const int* __restrict__ nflag, const int* __restrict__ flagged,
    int* __restrict__ idx) {
  __shared__ double sx[Dd];
  __shared__ double th[DMm];
  __shared__ double red[4][12];
  const int nf = *nflag;
  const int tid = threadIdx.x;
  const int wv = tid >> 6, ln = tid & 63;
  for (int f = blockIdx.x; f < nf; f += gridDim.x) {
    const int t = flagged[f];
    const int s = t & (Ss - 1);
    for (int l = tid; l < Dd; l += 256) {
      const double xa = (s > 0)      ? (double)x[(size_t)(t - 1) * Dd + l] : 0.0;
      const double xb =                (double)x[(size_t)t * Dd + l];
      const double xc = (s < Ss - 1) ? (double)x[(size_t)(t + 1) * Dd + l] : 0.0;
      sx[l] = (double)mk[l] * xa + (double)mk[Dd + l] * xb + (double)mk[2 * Dd + l] * xc;
    }
    __syncthreads();
    {
      double a0 = 0, a1 = 0, a2 = 0, a3 = 0;
      const float* wcol = Wo1 + tid;
      for (int d = 0; d < Dd; d += 4) {
        a0 += sx[d + 0] * (double)wcol[(size_t)(d + 0) * DMm];
        a1 += sx[d + 1] * (double)wcol[(size_t)(d + 1) * DMm];
        a2 += sx[d + 2] * (double)wcol[(size_t)(d + 2) * DMm];
        a3 += sx[d + 3] * (double)wcol[(size_t)(d + 3) * DMm];
      }
      th[tid] = tanh(((a0 + a1) + (a2 + a3)) + (double)bo1[tid]);
    }
    __syncthreads();
    double pr[Pp];
    const double tv = th[tid];
    #pragma unroll
    for (int p = 0; p < Pp; ++p) pr[p] = tv * (double)Wo2[tid * Pp + p];
    #pragma unroll
    for (int off = 32; off > 0; off >>= 1)
      #pragma unroll
      for (int p = 0; p < Pp; ++p) pr[p] += __shfl_xor(pr[p], off);
    if (ln == 0) {
      #pragma unroll
      for (int p = 0; p < Pp; ++p) red[wv][p] = pr[p];
    }
    __syncthreads();
    if (tid == 0) {
      double best = -1e300; int bi = 0;
      #pragma unroll
      for (int p = 0; p < Pp; ++p) {
        const double sv = red[0][p] + red[1][p] + red[2][p] + red[3][p] + (double)bo2[p];
        if (sv > best) { best = sv; bi = p; }
      }
      idx[t] = bi;
    }
    __syncthreads();
  }
}

// ---------------------------------------------------------------- group tokens by path
__global__ __launch_bounds__(256) void k_scatter(const int* __restrict__ idx,
    int* __restrict__ counts, int* __restrict__ tokenlist) {
  const int t = blockIdx.x * 256 + threadIdx.x;
  const int p = idx[t];
  const int pos = atomicAdd(&counts[p], 1);
  tokenlist[p * Tt + pos] = t;
}

// ---------------------------------------------------------------- in-place LayerNorm
__global__ __launch_bounds__(256) void k_ln(float* __restrict__ y,
    const float* __restrict__ gamma, const float* __restrict__ beta) {
  const int t = blockIdx.x;
  const int d = threadIdx.x << 2;
  float* row = y + (size_t)t * Dd;
  float4 v = *(float4*)(row + d);
  float s = v.x + v.y + v.z + v.w;
  float q = v.x * v.x + v.y * v.y + v.z * v.z + v.w * v.w;
  #pragma unroll
  for (int off = 32; off > 0; off >>= 1) {
    s += __shfl_xor(s, off);
    q += __shfl_xor(q, off);
  }
  __shared__ float ssum[4], sqq[4];
  const int wave = threadIdx.x >> 6, lane = threadIdx.x & 63;
  if (lane == 0) { ssum[wave] = s; sqq[wave] = q; }
  __syncthreads();
  s = ssum[0] + ssum[1] + ssum[2] + ssum[3];
  q = sqq[0] + sqq[1] + sqq[2] + sqq[3];
  const float mu = s * (1.f / Dd);
  const float var = q * (1.f / Dd) - mu * mu;
  const float inv = rsqrtf(var + EPSf);
  const float4 g = *(const float4*)(gamma + d);
  const float4 bt = *(const float4*)(beta + d);
  float4 o;
  o.x = (v.x - mu) * inv * g.x + bt.x;
  o.y = (v.y - mu) * inv * g.y + bt.y;
  o.z = (v.z - mu) * inv * g.z + bt.z;
  o.w = (v.w - mu) * inv * g.w + bt.w;
  *(float4*)(row + d) = o;
}

// ----------------------------------------------------------------
extern "C" void kernel_launch(void* const* d_in, const int* in_sizes, int n_in,
                              void* d_out, int out_size, void* d_ws, size_t ws_size,
                              hipStream_t stream) {
  (void)in_sizes; (void)n_in; (void)out_size; (void)ws_size;
  const float* x     = (const float*)d_in[0];
  const float* mk    = (const float*)d_in[1];
  const float* W1    = (const float*)d_in[2];
  const float* b1    = (const float*)d_in[3];
  const float* W2    = (const float*)d_in[4];
  const float* b2    = (const float*)d_in[5];
  const float* Wo1   = (const float*)d_in[6];
  const float* bo1   = (const float*)d_in[7];
  const float* Wo2   = (const float*)d_in[8];
  const float* bo2   = (const float*)d_in[9];
  const float* gamma = (const float*)d_in[10];
  const float* beta  = (const float*)d_in[11];
  float* out = (float*)d_out;

  size_t off = 0;
  auto alloc = [&](size_t bytes) -> void* {
    void* p = (char*)d_ws + off;
    off += (bytes + 255) & ~(size_t)255;
    return p;
  };
  unsigned short* xm_h   = (unsigned short*)alloc((size_t)Tt * Dd * 2);
  float*          hidden = (float*)alloc((size_t)Tt * DMm * 4);
  unsigned short* h1     = (unsigned short*)hidden;  // alias: hidden dead before h1 written
  unsigned short* W1t    = (unsigned short*)alloc((size_t)Pp * Dd * DMm * 2);
  unsigned short* W2t    = (unsigned short*)alloc((size_t)Pp * DMm * Dd * 2);
  unsigned short* Wo1t   = (unsigned short*)alloc((size_t)Dd * DMm * 2);
  int* idx      = (int*)alloc(Tt * 4);
  int* counts   = (int*)alloc(64 * 4);
  int* nflag    = counts + 16;
  int* flagged  = (int*)alloc(Tt * 4);
  int* tokenlist = (int*)alloc((size_t)Pp * Tt * 4);

  hipMemsetAsync(counts, 0, 256, stream);

  k_mix2<<<Tt, 256, 0, stream>>>(x, mk, xm_h);
  k_cvt_all<<<dim3(32, 32, 2 * Pp + 1), 256, 0, stream>>>(W1, W2, Wo1, W1t, W2t, Wo1t);

  k_gemm<Dd, DMm, 0><<<dim3(Tt / 128, DMm / 64, 1), 256, 0, stream>>>(
      xm_h, Wo1t, bo1, nullptr, hidden, nullptr, nullptr, nullptr);
  k_score<<<Tt / 4, 256, 0, stream>>>(hidden, Wo2, bo2, idx, nflag, flagged);
  k_rescue<<<256, 256, 0, stream>>>(x, mk, Wo1, bo1, Wo2, bo2, nflag, flagged, idx);
  k_scatter<<<Tt / 256, 256, 0, stream>>>(idx, counts, tokenlist);

  k_gemm<Dd, DMm, 1><<<dim3(Tt / 128, DMm / 64, Pp), 256, 0, stream>>>(
      xm_h, W1t, b1, nullptr, nullptr, h1, counts, tokenlist);
  k_gemm<DMm, Dd, 2><<<dim3(Tt / 128, Dd / 64, Pp), 256, 0, stream>>>(
      h1, W2t, b2, x, out, nullptr, counts, tokenlist);
  k_ln<<<Tt, 256, 0, stream>>>(out, gamma, beta);
}

// Round 5
// 183.108 us; speedup vs baseline: 1.2951x; 1.2369x over previous
//
#include <hip/hip_runtime.h>
#include <math.h>

#define Ss 2048
#define Dd 1024
#define Pp 9
#define DMm 256
#define Tt 8192
#define EPSf 1e-5f
#define BAND 1e-2f       // fp64-rescue band for argmax ties

typedef __attribute__((ext_vector_type(8))) __bf16 bf16x8;
typedef __attribute__((ext_vector_type(4))) float f32x4;

#define GLOBAL_AS __attribute__((address_space(1)))
#define LDS_AS __attribute__((address_space(3)))

#define MAXTILES 137     // sum_p ceil(cnt_p/64) <= 8192/64 + 9

__device__ __forceinline__ unsigned short bf16rn(float f) {
  unsigned int u = __float_as_uint(f);
  unsigned int r = (u + 0x7fffu + ((u >> 16) & 1u)) >> 16;
  return (unsigned short)r;
}

__device__ __forceinline__ void gload16(const void* g, void* l) {
  __builtin_amdgcn_global_load_lds((const GLOBAL_AS unsigned int*)g,
                                   (LDS_AS unsigned int*)l, 16, 0, 0);
}

// swizzled LDS short-offset for logical (row r, 16B-slot sl); row = 64 shorts (128B)
#define KSW(r, sl) (((r) << 6) + ((((sl) ^ ((r) & 7))) << 3))

// ---------------------------------------------------------------- mix -> bf16
__global__ __launch_bounds__(256) void k_mix2(const float* __restrict__ x,
    const float* __restrict__ mk, unsigned short* __restrict__ xh) {
  const int t = blockIdx.x;
  const int s = t & (Ss - 1);
  const int d = threadIdx.x << 2;
  const float* xc = x + (size_t)t * Dd + d;
  float4 vb = *(const float4*)xc;
  float4 va = make_float4(0.f, 0.f, 0.f, 0.f);
  float4 vc = make_float4(0.f, 0.f, 0.f, 0.f);
  if (s > 0)      va = *(const float4*)(xc - Dd);
  if (s < Ss - 1) vc = *(const float4*)(xc + Dd);
  const float4 k0 = *(const float4*)(mk + d);
  const float4 k1 = *(const float4*)(mk + Dd + d);
  const float4 k2 = *(const float4*)(mk + 2 * Dd + d);
  float4 o;
  o.x = k0.x * va.x + k1.x * vb.x + k2.x * vc.x;
  o.y = k0.y * va.y + k1.y * vb.y + k2.y * vc.y;
  o.z = k0.z * va.z + k1.z * vb.z + k2.z * vc.z;
  o.w = k0.w * va.w + k1.w * vb.w + k2.w * vc.w;
  ushort4 h;
  h.x = bf16rn(o.x); h.y = bf16rn(o.y); h.z = bf16rn(o.z); h.w = bf16rn(o.w);
  *(ushort4*)(xh + (size_t)t * Dd + d) = h;
}

// ---------------------------------------------------------------- all weight converts in one launch
__global__ __launch_bounds__(256) void k_cvt_all(
    const float* __restrict__ W1, const float* __restrict__ W2,
    const float* __restrict__ Wo1,
    unsigned short* __restrict__ W1t, unsigned short* __restrict__ W2t,
    unsigned short* __restrict__ Wo1t) {
  const int z = blockIdx.z;
  const float* in; unsigned short* outp; int R, C;
  if (z < Pp)            { in = W1;  outp = W1t;  R = Dd;  C = DMm; }
  else if (z < 2 * Pp)   { in = W2;  outp = W2t;  R = DMm; C = Dd;  }
  else                   { in = Wo1; outp = Wo1t; R = Dd;  C = DMm; }
  const int zi = (z < Pp) ? z : ((z < 2 * Pp) ? z - Pp : 0);
  const int r0 = blockIdx.x * 32, c0 = blockIdx.y * 32;
  if (r0 >= R || c0 >= C) return;
  const size_t zo = (size_t)zi * R * C;
  __shared__ float tile[32][33];
  const int tr = threadIdx.x >> 3, tc = (threadIdx.x & 7) << 2;
  float4 v = *(const float4*)(in + zo + (size_t)(r0 + tr) * C + c0 + tc);
  tile[tr][tc] = v.x; tile[tr][tc + 1] = v.y; tile[tr][tc + 2] = v.z; tile[tr][tc + 3] = v.w;
  __syncthreads();
  ushort4 h;
  h.x = bf16rn(tile[tc + 0][tr]); h.y = bf16rn(tile[tc + 1][tr]);
  h.z = bf16rn(tile[tc + 2][tr]); h.w = bf16rn(tile[tc + 3][tr]);
  *(ushort4*)(outp + zo + (size_t)(c0 + tr) * R + r0 + tc) = h;
}

// ---------------------------------------------------------------- pipelined MFMA GEMM, 64x64 tile, BK=64
// All blocks real: grouped blocks self-map blockIdx.x -> (path, tile) via counts scan.
// MODE 0: outf = tanh(acc+bias)   MODE 1: outh = bf16(acc+bias)   MODE 2: outf = acc+bias+resid
template<int KTOT, int NTOT, int MODE, bool GROUPED>
__global__ __launch_bounds__(256) void k_gemm(
    const unsigned short* __restrict__ A,
    const unsigned short* __restrict__ Bt,
    const float* __restrict__ bias,
    const float* __restrict__ resid,
    float* __restrict__ outf, unsigned short* __restrict__ outh,
    const int* __restrict__ counts, const int* __restrict__ tokenlist) {
  int p = 0, ti = blockIdx.x, cnt = Tt;
  if (GROUPED) {
    for (p = 0; p < Pp; ++p) {
      cnt = counts[p];
      const int nt = (cnt + 63) >> 6;
      if (ti < nt) break;
      ti -= nt;
    }
    if (p == Pp) return;
  }
  const int tile0 = ti * 64;
  __shared__ int tl[64];
  __shared__ __align__(16) unsigned short As[2][64 * 64];  // 2 x 8 KB
  __shared__ __align__(16) unsigned short Bs[2][64 * 64];  // 2 x 8 KB
  const int tid = threadIdx.x;
  if (tid < 64) {
    const int li = tile0 + tid;
    if (GROUPED) tl[tid] = (li < cnt) ? tokenlist[p * Tt + li] : tokenlist[p * Tt];
    else         tl[tid] = li;
  }
  __syncthreads();
  const int w = tid >> 6, lane = tid & 63;
  const int fr = lane & 15, fs = lane >> 4;
  const int wr = w >> 1, wc = w & 1;
  const int n0 = blockIdx.y * 64;
  const unsigned short* Bp0 = Bt + (size_t)p * NTOT * KTOT + (size_t)n0 * KTOT;
  // staging: unit u = i*256 + tid ; global (row u>>3, slot (u&7)^(row&7)) ; LDS linear at u*16B
  const unsigned short* srcA[2];
  const unsigned short* srcB[2];
  #pragma unroll
  for (int i = 0; i < 2; ++i) {
    const int u = i * 256 + tid, r = u >> 3, sl = (u & 7) ^ (r & 7);
    srcA[i] = A + (size_t)tl[r] * KTOT + sl * 8;
    srcB[i] = Bp0 + (size_t)r * KTOT + sl * 8;
  }
  const int ldsW = w * 512;  // wave-uniform dest offset (shorts)
  // fragment read offsets (swizzled)
  int aoff[2][2], boff[2][2];
  #pragma unroll
  for (int m = 0; m < 2; ++m)
    #pragma unroll
    for (int kk = 0; kk < 2; ++kk) {
      aoff[m][kk] = KSW(wr * 32 + m * 16 + fr, kk * 4 + fs);
      boff[m][kk] = KSW(wc * 32 + m * 16 + fr, kk * 4 + fs);
    }

#define STAGE(b, kb) do { \
    gload16(srcA[0] + (kb), &As[b][0] + ldsW); \
    gload16(srcA[1] + (kb), &As[b][0] + 2048 + ldsW); \
    gload16(srcB[0] + (kb), &Bs[b][0] + ldsW); \
    gload16(srcB[1] + (kb), &Bs[b][0] + 2048 + ldsW); \
  } while (0)

  f32x4 acc[2][2] = {};
  const int NS = KTOT / 64;
  STAGE(0, 0);
  for (int s = 0; s < NS; ++s) {
    const int buf = s & 1;
    if (s + 1 < NS) {
      STAGE(buf ^ 1, (s + 1) * 64);
      asm volatile("s_waitcnt vmcnt(4)" ::: "memory");   // current buf's 4 loads done
    } else {
      asm volatile("s_waitcnt vmcnt(0)" ::: "memory");
    }
    __builtin_amdgcn_s_barrier();
    __builtin_amdgcn_sched_barrier(0);
    const unsigned short* Ab = &As[buf][0];
    const unsigned short* Bb_ = &Bs[buf][0];
    bf16x8 a[2][2], b[2][2];
    #pragma unroll
    for (int m = 0; m < 2; ++m)
      #pragma unroll
      for (int kk = 0; kk < 2; ++kk) {
        a[m][kk] = *(const bf16x8*)&Ab[aoff[m][kk]];
        b[m][kk] = *(const bf16x8*)&Bb_[boff[m][kk]];
      }
    #pragma unroll
    for (int kk = 0; kk < 2; ++kk)
      #pragma unroll
      for (int m = 0; m < 2; ++m)
        #pragma unroll
        for (int n = 0; n < 2; ++n)
          acc[m][n] = __builtin_amdgcn_mfma_f32_16x16x32_bf16(a[m][kk], b[n][kk], acc[m][n], 0, 0, 0);
    __builtin_amdgcn_s_barrier();   // reads of buf done before restage
  }
#undef STAGE

  // C/D layout: col = fr, row = fs*4 + j
  const float* bias_z = bias + (size_t)p * NTOT;
  #pragma unroll
  for (int m = 0; m < 2; ++m) {
    #pragma unroll
    for (int j = 0; j < 4; ++j) {
      const int rr = wr * 32 + m * 16 + fs * 4 + j;
      const int li = tile0 + rr;
      if (GROUPED && li >= cnt) continue;
      const int t = tl[rr];
      #pragma unroll
      for (int n = 0; n < 2; ++n) {
        const int c = n0 + wc * 32 + n * 16 + fr;
        const float v = acc[m][n][j] + bias_z[c];
        if (MODE == 0)      outf[(size_t)t * NTOT + c] = tanhf(v);
        else if (MODE == 1) outh[(size_t)t * NTOT + c] = bf16rn(v);
        else                outf[(size_t)t * NTOT + c] = v + resid[(size_t)t * NTOT + c];
      }
    }
  }
}

// ---------------------------------------------------------------- scores + argmax + near-tie flag
__global__ __launch_bounds__(256) void k_score(const float* __restrict__ hidden,
    const float* __restrict__ Wo2, const float* __restrict__ bo2,
    int* __restrict__ idx, int* __restrict__ nflag, int* __restrict__ flagged) {
  __shared__ float sW[DMm * Pp];
  const int tid = threadIdx.x;
  for (int l = tid; l < DMm * Pp; l += 256) sW[l] = Wo2[l];
  __syncthreads();
  const int wave = tid >> 6, lane = tid & 63;
  const int t = blockIdx.x * 4 + wave;
  const float4 h = *(const float4*)(hidden + (size_t)t * DMm + lane * 4);
  const int m = lane * 4;
  float part[Pp];
  #pragma unroll
  for (int pp = 0; pp < Pp; ++pp)
    part[pp] = h.x * sW[(m + 0) * Pp + pp] + h.y * sW[(m + 1) * Pp + pp]
             + h.z * sW[(m + 2) * Pp + pp] + h.w * sW[(m + 3) * Pp + pp];
  #pragma unroll
  for (int off = 32; off > 0; off >>= 1)
    #pragma unroll
    for (int pp = 0; pp < Pp; ++pp)
      part[pp] += __shfl_xor(part[pp], off);
  if (lane == 0) {
    float best = -1e30f, second = -1e30f;
    int bi = 0;
    #pragma unroll
    for (int pp = 0; pp < Pp; ++pp) {
      const float sc = part[pp] + bo2[pp];
      if (sc > best) { second = best; best = sc; bi = pp; }
      else if (sc > second) second = sc;
    }
    idx[t] = bi;
    if (best - second < BAND) {
      const int pos = atomicAdd(nflag, 1);
      flagged[pos] = t;
    }
  }
}

// ---------------------------------------------------------------- fp64 rescue (parallelized)
__global__ __launch_bounds__(256) void k_rescue(const float* __restrict__ x,
    const float* __restrict__ mk,
    const float* __restrict__ Wo1, const float* __restrict__ bo1,
    const float* __restrict__ Wo2, const float* __restrict__ bo2,
    const int* __restrict__ nflag, const int* __restrict__ flagged,
    int* __restrict__ idx) {
  __shared__ double sx[Dd];
  __shared__ double th[DMm];
  __shared__ double red[4][12];
  const int nf = *nflag;
  const int tid = threadIdx.x;
  const int wv = tid >> 6, ln = tid & 63;
  for (int f = blockIdx.x; f < nf; f += gridDim.x) {
    const int t = flagged[f];
    const int s = t & (Ss - 1);
    for (int l = tid; l < Dd; l += 256) {
      const double xa = (s > 0)      ? (double)x[(size_t)(t - 1) * Dd + l] : 0.0;
      const double xb =                (double)x[(size_t)t * Dd + l];
      const double xc = (s < Ss - 1) ? (double)x[(size_t)(t + 1) * Dd + l] : 0.0;
      sx[l] = (double)mk[l] * xa + (double)mk[Dd + l] * xb + (double)mk[2 * Dd + l] * xc;
    }
    __syncthreads();
    {
      double a0 = 0, a1 = 0, a2 = 0, a3 = 0;
      const float* wcol = Wo1 + tid;
      for (int d = 0; d < Dd; d += 4) {
        a0 += sx[d + 0] * (double)wcol[(size_t)(d + 0) * DMm];
        a1 += sx[d + 1] * (double)wcol[(size_t)(d + 1) * DMm];
        a2 += sx[d + 2] * (double)wcol[(size_t)(d + 2) * DMm];
        a3 += sx[d + 3] * (double)wcol[(size_t)(d + 3) * DMm];
      }
      th[tid] = tanh(((a0 + a1) + (a2 + a3)) + (double)bo1[tid]);
    }
    __syncthreads();
    double pr[Pp];
    const double tv = th[tid];
    #pragma unroll
    for (int p = 0; p < Pp; ++p) pr[p] = tv * (double)Wo2[tid * Pp + p];
    #pragma unroll
    for (int off = 32; off > 0; off >>= 1)
      #pragma unroll
      for (int p = 0; p < Pp; ++p) pr[p] += __shfl_xor(pr[p], off);
    if (ln == 0) {
      #pragma unroll
      for (int p = 0; p < Pp; ++p) red[wv][p] = pr[p];
    }
    __syncthreads();
    if (tid == 0) {
      double best = -1e300; int bi = 0;
      #pragma unroll
      for (int p = 0; p < Pp; ++p) {
        const double sv = red[0][p] + red[1][p] + red[2][p] + red[3][p] + (double)bo2[p];
        if (sv > best) { best = sv; bi = p; }
      }
      idx[t] = bi;
    }
    __syncthreads();
  }
}

// ---------------------------------------------------------------- group tokens by path
__global__ __launch_bounds__(256) void k_scatter(const int* __restrict__ idx,
    int* __restrict__ counts, int* __restrict__ tokenlist) {
  const int t = blockIdx.x * 256 + threadIdx.x;
  const int p = idx[t];
  const int pos = atomicAdd(&counts[p], 1);
  tokenlist[p * Tt + pos] = t;
}

// ---------------------------------------------------------------- in-place LayerNorm
__global__ __launch_bounds__(256) void k_ln(float* __restrict__ y,
    const float* __restrict__ gamma, const float* __restrict__ beta) {
  const int t = blockIdx.x;
  const int d = threadIdx.x << 2;
  float* row = y + (size_t)t * Dd;
  float4 v = *(float4*)(row + d);
  float s = v.x + v.y + v.z + v.w;
  float q = v.x * v.x + v.y * v.y + v.z * v.z + v.w * v.w;
  #pragma unroll
  for (int off = 32; off > 0; off >>= 1) {
    s += __shfl_xor(s, off);
    q += __shfl_xor(q, off);
  }
  __shared__ float ssum[4], sqq[4];
  const int wave = threadIdx.x >> 6, lane = threadIdx.x & 63;
  if (lane == 0) { ssum[wave] = s; sqq[wave] = q; }
  __syncthreads();
  s = ssum[0] + ssum[1] + ssum[2] + ssum[3];
  q = sqq[0] + sqq[1] + sqq[2] + sqq[3];
  const float mu = s * (1.f / Dd);
  const float var = q * (1.f / Dd) - mu * mu;
  const float inv = rsqrtf(var + EPSf);
  const float4 g = *(const float4*)(gamma + d);
  const float4 bt = *(const float4*)(beta + d);
  float4 o;
  o.x = (v.x - mu) * inv * g.x + bt.x;
  o.y = (v.y - mu) * inv * g.y + bt.y;
  o.z = (v.z - mu) * inv * g.z + bt.z;
  o.w = (v.w - mu) * inv * g.w + bt.w;
  *(float4*)(row + d) = o;
}

// ----------------------------------------------------------------
extern "C" void kernel_launch(void* const* d_in, const int* in_sizes, int n_in,
                              void* d_out, int out_size, void* d_ws, size_t ws_size,
                              hipStream_t stream) {
  (void)in_sizes; (void)n_in; (void)out_size; (void)ws_size;
  const float* x     = (const float*)d_in[0];
  const float* mk    = (const float*)d_in[1];
  const float* W1    = (const float*)d_in[2];
  const float* b1    = (const float*)d_in[3];
  const float* W2    = (const float*)d_in[4];
  const float* b2    = (const float*)d_in[5];
  const float* Wo1   = (const float*)d_in[6];
  const float* bo1   = (const float*)d_in[7];
  const float* Wo2   = (const float*)d_in[8];
  const float* bo2   = (const float*)d_in[9];
  const float* gamma = (const float*)d_in[10];
  const float* beta  = (const float*)d_in[11];
  float* out = (float*)d_out;

  size_t off = 0;
  auto alloc = [&](size_t bytes) -> void* {
    void* p = (char*)d_ws + off;
    off += (bytes + 255) & ~(size_t)255;
    return p;
  };
  unsigned short* xm_h   = (unsigned short*)alloc((size_t)Tt * Dd * 2);
  float*          hidden = (float*)alloc((size_t)Tt * DMm * 4);
  unsigned short* h1     = (unsigned short*)hidden;  // alias: hidden dead before h1 written
  unsigned short* W1t    = (unsigned short*)alloc((size_t)Pp * Dd * DMm * 2);
  unsigned short* W2t    = (unsigned short*)alloc((size_t)Pp * DMm * Dd * 2);
  unsigned short* Wo1t   = (unsigned short*)alloc((size_t)Dd * DMm * 2);
  int* idx      = (int*)alloc(Tt * 4);
  int* counts   = (int*)alloc(64 * 4);
  int* nflag    = counts + 16;
  int* flagged  = (int*)alloc(Tt * 4);
  int* tokenlist = (int*)alloc((size_t)Pp * Tt * 4);

  hipMemsetAsync(counts, 0, 256, stream);

  k_mix2<<<Tt, 256, 0, stream>>>(x, mk, xm_h);
  k_cvt_all<<<dim3(32, 32, 2 * Pp + 1), 256, 0, stream>>>(W1, W2, Wo1, W1t, W2t, Wo1t);

  k_gemm<Dd, DMm, 0, false><<<dim3(Tt / 64, DMm / 64), 256, 0, stream>>>(
      xm_h, Wo1t, bo1, nullptr, hidden, nullptr, nullptr, nullptr);
  k_score<<<Tt / 4, 256, 0, stream>>>(hidden, Wo2, bo2, idx, nflag, flagged);
  k_rescue<<<256, 256, 0, stream>>>(x, mk, Wo1, bo1, Wo2, bo2, nflag, flagged, idx);
  k_scatter<<<Tt / 256, 256, 0, stream>>>(idx, counts, tokenlist);

  k_gemm<Dd, DMm, 1, true><<<dim3(MAXTILES, DMm / 64), 256, 0, stream>>>(
      xm_h, W1t, b1, nullptr, nullptr, h1, counts, tokenlist);
  k_gemm<DMm, Dd, 2, true><<<dim3(MAXTILES, Dd / 64), 256, 0, stream>>>(
      h1, W2t, b2, x, out, nullptr, counts, tokenlist);
  k_ln<<<Tt, 256, 0, stream>>>(out, gamma, beta);
}

// Round 6
// 178.807 us; speedup vs baseline: 1.3263x; 1.0241x over previous
//
#include <hip/hip_runtime.h>
#include <math.h>

#define Ss 2048
#define Dd 1024
#define Pp 9
#define DMm 256
#define Tt 8192
#define EPSf 1e-5f
#define BAND 1e-2f       // fp64-rescue band for argmax ties

typedef __attribute__((ext_vector_type(8))) __bf16 bf16x8;
typedef __attribute__((ext_vector_type(4))) float f32x4;

#define GLOBAL_AS __attribute__((address_space(1)))
#define LDS_AS __attribute__((address_space(3)))

#define MAXTILES 137     // sum_p ceil(cnt_p/64) <= 8192/64 + 9

__device__ __forceinline__ unsigned short bf16rn(float f) {
  unsigned int u = __float_as_uint(f);
  unsigned int r = (u + 0x7fffu + ((u >> 16) & 1u)) >> 16;
  return (unsigned short)r;
}

__device__ __forceinline__ void gload16(const void* g, void* l) {
  __builtin_amdgcn_global_load_lds((const GLOBAL_AS unsigned int*)g,
                                   (LDS_AS unsigned int*)l, 16, 0, 0);
}

// swizzled LDS short-offset for logical (row r, 16B-slot sl); row = 64 shorts (128B)
#define KSW(r, sl) (((r) << 6) + ((((sl) ^ ((r) & 7))) << 3))

// ---------------------------------------------------------------- mix -> bf16 (+ zero counts)
__global__ __launch_bounds__(256) void k_mix2(const float* __restrict__ x,
    const float* __restrict__ mk, unsigned short* __restrict__ xh,
    int* __restrict__ counts) {
  if (blockIdx.x == 0 && threadIdx.x < 64) counts[threadIdx.x] = 0;
  const int t = blockIdx.x;
  const int s = t & (Ss - 1);
  const int d = threadIdx.x << 2;
  const float* xc = x + (size_t)t * Dd + d;
  float4 vb = *(const float4*)xc;
  float4 va = make_float4(0.f, 0.f, 0.f, 0.f);
  float4 vc = make_float4(0.f, 0.f, 0.f, 0.f);
  if (s > 0)      va = *(const float4*)(xc - Dd);
  if (s < Ss - 1) vc = *(const float4*)(xc + Dd);
  const float4 k0 = *(const float4*)(mk + d);
  const float4 k1 = *(const float4*)(mk + Dd + d);
  const float4 k2 = *(const float4*)(mk + 2 * Dd + d);
  float4 o;
  o.x = k0.x * va.x + k1.x * vb.x + k2.x * vc.x;
  o.y = k0.y * va.y + k1.y * vb.y + k2.y * vc.y;
  o.z = k0.z * va.z + k1.z * vb.z + k2.z * vc.z;
  o.w = k0.w * va.w + k1.w * vb.w + k2.w * vc.w;
  ushort4 h;
  h.x = bf16rn(o.x); h.y = bf16rn(o.y); h.z = bf16rn(o.z); h.w = bf16rn(o.w);
  *(ushort4*)(xh + (size_t)t * Dd + d) = h;
}

// ---------------------------------------------------------------- all weight converts in one launch
__global__ __launch_bounds__(256) void k_cvt_all(
    const float* __restrict__ W1, const float* __restrict__ W2,
    const float* __restrict__ Wo1,
    unsigned short* __restrict__ W1t, unsigned short* __restrict__ W2t,
    unsigned short* __restrict__ Wo1t) {
  const int z = blockIdx.z;
  const float* in; unsigned short* outp; int R, C;
  if (z < Pp)            { in = W1;  outp = W1t;  R = Dd;  C = DMm; }
  else if (z < 2 * Pp)   { in = W2;  outp = W2t;  R = DMm; C = Dd;  }
  else                   { in = Wo1; outp = Wo1t; R = Dd;  C = DMm; }
  const int zi = (z < Pp) ? z : ((z < 2 * Pp) ? z - Pp : 0);
  const int r0 = blockIdx.x * 32, c0 = blockIdx.y * 32;
  if (r0 >= R || c0 >= C) return;
  const size_t zo = (size_t)zi * R * C;
  __shared__ float tile[32][33];
  const int tr = threadIdx.x >> 3, tc = (threadIdx.x & 7) << 2;
  float4 v = *(const float4*)(in + zo + (size_t)(r0 + tr) * C + c0 + tc);
  tile[tr][tc] = v.x; tile[tr][tc + 1] = v.y; tile[tr][tc + 2] = v.z; tile[tr][tc + 3] = v.w;
  __syncthreads();
  ushort4 h;
  h.x = bf16rn(tile[tc + 0][tr]); h.y = bf16rn(tile[tc + 1][tr]);
  h.z = bf16rn(tile[tc + 2][tr]); h.w = bf16rn(tile[tc + 3][tr]);
  *(ushort4*)(outp + zo + (size_t)(c0 + tr) * R + r0 + tc) = h;
}

// ---------------------------------------------------------------- pipelined MFMA GEMM, 64x128 tile, BK=64
// Packed grid: grouped blocks self-map blockIdx.x -> (path, tile) via counts scan.
// MODE 0: outf = tanh(acc+bias)   MODE 1: outh = bf16(acc+bias)   MODE 2: outf = acc+bias+resid
template<int KTOT, int NTOT, int MODE, bool GROUPED>
__global__ __launch_bounds__(256) void k_gemm(
    const unsigned short* __restrict__ A,
    const unsigned short* __restrict__ Bt,
    const float* __restrict__ bias,
    const float* __restrict__ resid,
    float* __restrict__ outf, unsigned short* __restrict__ outh,
    const int* __restrict__ counts, const int* __restrict__ tokenlist) {
  int p = 0, ti = blockIdx.x, cnt = Tt;
  if (GROUPED) {
    for (p = 0; p < Pp; ++p) {
      cnt = counts[p];
      const int nt = (cnt + 63) >> 6;
      if (ti < nt) break;
      ti -= nt;
    }
    if (p == Pp) return;
  }
  const int tile0 = ti * 64;
  __shared__ int tl[64];
  __shared__ __align__(16) unsigned short As[2][64 * 64];   // 2 x 8 KB
  __shared__ __align__(16) unsigned short Bs[2][128 * 64];  // 2 x 16 KB
  const int tid = threadIdx.x;
  if (tid < 64) {
    const int li = tile0 + tid;
    if (GROUPED) tl[tid] = (li < cnt) ? tokenlist[p * Tt + li] : tokenlist[p * Tt];
    else         tl[tid] = li;
  }
  __syncthreads();
  const int w = tid >> 6, lane = tid & 63;
  const int fr = lane & 15, fs = lane >> 4;
  const int wr = w >> 1, wc = w & 1;
  const int n0 = blockIdx.y * 128;
  const unsigned short* Bp0 = Bt + (size_t)p * NTOT * KTOT + (size_t)n0 * KTOT;
  // staging: unit u ; global (row u>>3, slot (u&7)^(row&7)) ; LDS linear at u*16B
  const unsigned short* srcA[2];
  #pragma unroll
  for (int i = 0; i < 2; ++i) {
    const int u = i * 256 + tid, r = u >> 3, sl = (u & 7) ^ (r & 7);
    srcA[i] = A + (size_t)tl[r] * KTOT + sl * 8;
  }
  const unsigned short* srcB[4];
  #pragma unroll
  for (int i = 0; i < 4; ++i) {
    const int u = i * 256 + tid, r = u >> 3, sl = (u & 7) ^ (r & 7);
    srcB[i] = Bp0 + (size_t)r * KTOT + sl * 8;
  }
  const int ldsW = w * 512;  // wave-uniform dest offset (shorts)
  // fragment read offsets (swizzled)
  int aoff[2][2], boff[4][2];
  #pragma unroll
  for (int m = 0; m < 2; ++m)
    #pragma unroll
    for (int kk = 0; kk < 2; ++kk)
      aoff[m][kk] = KSW(wr * 32 + m * 16 + fr, kk * 4 + fs);
  #pragma unroll
  for (int n = 0; n < 4; ++n)
    #pragma unroll
    for (int kk = 0; kk < 2; ++kk)
      boff[n][kk] = KSW(wc * 64 + n * 16 + fr, kk * 4 + fs);

#define STAGE(b, kb) do { \
    gload16(srcA[0] + (kb), &As[b][0] + ldsW); \
    gload16(srcA[1] + (kb), &As[b][0] + 2048 + ldsW); \
    gload16(srcB[0] + (kb), &Bs[b][0] + ldsW); \
    gload16(srcB[1] + (kb), &Bs[b][0] + 2048 + ldsW); \
    gload16(srcB[2] + (kb), &Bs[b][0] + 4096 + ldsW); \
    gload16(srcB[3] + (kb), &Bs[b][0] + 6144 + ldsW); \
  } while (0)

  f32x4 acc[2][4] = {};
  const int NS = KTOT / 64;
  STAGE(0, 0);
  for (int s = 0; s < NS; ++s) {
    const int buf = s & 1;
    if (s + 1 < NS) {
      STAGE(buf ^ 1, (s + 1) * 64);
      asm volatile("s_waitcnt vmcnt(6)" ::: "memory");   // current buf's 6 loads done
    } else {
      asm volatile("s_waitcnt vmcnt(0)" ::: "memory");
    }
    __builtin_amdgcn_s_barrier();
    __builtin_amdgcn_sched_barrier(0);
    const unsigned short* Ab = &As[buf][0];
    const unsigned short* Bb_ = &Bs[buf][0];
    bf16x8 a[2][2], b[4][2];
    #pragma unroll
    for (int m = 0; m < 2; ++m)
      #pragma unroll
      for (int kk = 0; kk < 2; ++kk)
        a[m][kk] = *(const bf16x8*)&Ab[aoff[m][kk]];
    #pragma unroll
    for (int n = 0; n < 4; ++n)
      #pragma unroll
      for (int kk = 0; kk < 2; ++kk)
        b[n][kk] = *(const bf16x8*)&Bb_[boff[n][kk]];
    #pragma unroll
    for (int kk = 0; kk < 2; ++kk)
      #pragma unroll
      for (int m = 0; m < 2; ++m)
        #pragma unroll
        for (int n = 0; n < 4; ++n)
          acc[m][n] = __builtin_amdgcn_mfma_f32_16x16x32_bf16(a[m][kk], b[n][kk], acc[m][n], 0, 0, 0);
    __builtin_amdgcn_s_barrier();   // reads of buf done before restage
  }
#undef STAGE

  // C/D layout: col = fr, row = fs*4 + j
  const float* bias_z = bias + (size_t)p * NTOT;
  #pragma unroll
  for (int m = 0; m < 2; ++m) {
    #pragma unroll
    for (int j = 0; j < 4; ++j) {
      const int rr = wr * 32 + m * 16 + fs * 4 + j;
      const int li = tile0 + rr;
      if (GROUPED && li >= cnt) continue;
      const int t = tl[rr];
      #pragma unroll
      for (int n = 0; n < 4; ++n) {
        const int c = n0 + wc * 64 + n * 16 + fr;
        const float v = acc[m][n][j] + bias_z[c];
        if (MODE == 0)      outf[(size_t)t * NTOT + c] = tanhf(v);
        else if (MODE == 1) outh[(size_t)t * NTOT + c] = bf16rn(v);
        else                outf[(size_t)t * NTOT + c] = v + resid[(size_t)t * NTOT + c];
      }
    }
  }
}

// ---------------------------------------------------------------- scores + argmax + near-tie flag
__global__ __launch_bounds__(256) void k_score(const float* __restrict__ hidden,
    const float* __restrict__ Wo2, const float* __restrict__ bo2,
    int* __restrict__ idx, int* __restrict__ nflag, int* __restrict__ flagged) {
  __shared__ float sW[DMm * Pp];
  const int tid = threadIdx.x;
  for (int l = tid; l < DMm * Pp; l += 256) sW[l] = Wo2[l];
  __syncthreads();
  const int wave = tid >> 6, lane = tid & 63;
  const int t = blockIdx.x * 4 + wave;
  const float4 h = *(const float4*)(hidden + (size_t)t * DMm + lane * 4);
  const int m = lane * 4;
  float part[Pp];
  #pragma unroll
  for (int pp = 0; pp < Pp; ++pp)
    part[pp] = h.x * sW[(m + 0) * Pp + pp] + h.y * sW[(m + 1) * Pp + pp]
             + h.z * sW[(m + 2) * Pp + pp] + h.w * sW[(m + 3) * Pp + pp];
  #pragma unroll
  for (int off = 32; off > 0; off >>= 1)
    #pragma unroll
    for (int pp = 0; pp < Pp; ++pp)
      part[pp] += __shfl_xor(part[pp], off);
  if (lane == 0) {
    float best = -1e30f, second = -1e30f;
    int bi = 0;
    #pragma unroll
    for (int pp = 0; pp < Pp; ++pp) {
      const float sc = part[pp] + bo2[pp];
      if (sc > best) { second = best; best = sc; bi = pp; }
      else if (sc > second) second = sc;
    }
    idx[t] = bi;
    if (best - second < BAND) {
      const int pos = atomicAdd(nflag, 1);
      flagged[pos] = t;
    }
  }
}

// ---------------------------------------------------------------- fp64 rescue (parallelized)
__global__ __launch_bounds__(256) void k_rescue(const float* __restrict__ x,
    const float* __restrict__ mk,
    const float* __restrict__ Wo1, const float* __restrict__ bo1,
    const float* __restrict__ Wo2, const float* __restrict__ bo2,
    const int* __restrict__ nflag, const int* __restrict__ flagged,
    int* __restrict__ idx) {
  __shared__ double sx[Dd];
  __shared__ double th[DMm];
  __shared__ double red[4][12];
  const int nf = *nflag;
  const int tid = threadIdx.x;
  const int wv = tid >> 6, ln = tid & 63;
  for (int f = blockIdx.x; f < nf; f += gridDim.x) {
    const int t = flagged[f];
    const int s = t & (Ss - 1);
    for (int l = tid; l < Dd; l += 256) {
      const double xa = (s > 0)      ? (double)x[(size_t)(t - 1) * Dd + l] : 0.0;
      const double xb =                (double)x[(size_t)t * Dd + l];
      const double xc = (s < Ss - 1) ? (double)x[(size_t)(t + 1) * Dd + l] : 0.0;
      sx[l] = (double)mk[l] * xa + (double)mk[Dd + l] * xb + (double)mk[2 * Dd + l] * xc;
    }
    __syncthreads();
    {
      double a0 = 0, a1 = 0, a2 = 0, a3 = 0;
      const float* wcol = Wo1 + tid;
      for (int d = 0; d < Dd; d += 4) {
        a0 += sx[d + 0] * (double)wcol[(size_t)(d + 0) * DMm];
        a1 += sx[d + 1] * (double)wcol[(size_t)(d + 1) * DMm];
        a2 += sx[d + 2] * (double)wcol[(size_t)(d + 2) * DMm];
        a3 += sx[d + 3] * (double)wcol[(size_t)(d + 3) * DMm];
      }
      th[tid] = tanh(((a0 + a1) + (a2 + a3)) + (double)bo1[tid]);
    }
    __syncthreads();
    double pr[Pp];
    const double tv = th[tid];
    #pragma unroll
    for (int p = 0; p < Pp; ++p) pr[p] = tv * (double)Wo2[tid * Pp + p];
    #pragma unroll
    for (int off = 32; off > 0; off >>= 1)
      #pragma unroll
      for (int p = 0; p < Pp; ++p) pr[p] += __shfl_xor(pr[p], off);
    if (ln == 0) {
      #pragma unroll
      for (int p = 0; p < Pp; ++p) red[wv][p] = pr[p];
    }
    __syncthreads();
    if (tid == 0) {
      double best = -1e300; int bi = 0;
      #pragma unroll
      for (int p = 0; p < Pp; ++p) {
        const double sv = red[0][p] + red[1][p] + red[2][p] + red[3][p] + (double)bo2[p];
        if (sv > best) { best = sv; bi = p; }
      }
      idx[t] = bi;
    }
    __syncthreads();
  }
}

// ---------------------------------------------------------------- group tokens by path
__global__ __launch_bounds__(256) void k_scatter(const int* __restrict__ idx,
    int* __restrict__ counts, int* __restrict__ tokenlist) {
  const int t = blockIdx.x * 256 + threadIdx.x;
  const int p = idx[t];
  const int pos = atomicAdd(&counts[p], 1);
  tokenlist[p * Tt + pos] = t;
}

// ---------------------------------------------------------------- in-place LayerNorm
__global__ __launch_bounds__(256) void k_ln(float* __restrict__ y,
    const float* __restrict__ gamma, const float* __restrict__ beta) {
  const int t = blockIdx.x;
  const int d = threadIdx.x << 2;
  float* row = y + (size_t)t * Dd;
  float4 v = *(float4*)(row + d);
  float s = v.x + v.y + v.z + v.w;
  float q = v.x * v.x + v.y * v.y + v.z * v.z + v.w * v.w;
  #pragma unroll
  for (int off = 32; off > 0; off >>= 1) {
    s += __shfl_xor(s, off);
    q += __shfl_xor(q, off);
  }
  __shared__ float ssum[4], sqq[4];
  const int wave = threadIdx.x >> 6, lane = threadIdx.x & 63;
  if (lane == 0) { ssum[wave] = s; sqq[wave] = q; }
  __syncthreads();
  s = ssum[0] + ssum[1] + ssum[2] + ssum[3];
  q = sqq[0] + sqq[1] + sqq[2] + sqq[3];
  const float mu = s * (1.f / Dd);
  const float var = q * (1.f / Dd) - mu * mu;
  const float inv = rsqrtf(var + EPSf);
  const float4 g = *(const float4*)(gamma + d);
  const float4 bt = *(const float4*)(beta + d);
  float4 o;
  o.x = (v.x - mu) * inv * g.x + bt.x;
  o.y = (v.y - mu) * inv * g.y + bt.y;
  o.z = (v.z - mu) * inv * g.z + bt.z;
  o.w = (v.w - mu) * inv * g.w + bt.w;
  *(float4*)(row + d) = o;
}

// ----------------------------------------------------------------
extern "C" void kernel_launch(void* const* d_in, const int* in_sizes, int n_in,
                              void* d_out, int out_size, void* d_ws, size_t ws_size,
                              hipStream_t stream) {
  (void)in_sizes; (void)n_in; (void)out_size; (void)ws_size;
  const float* x     = (const float*)d_in[0];
  const float* mk    = (const float*)d_in[1];
  const float* W1    = (const float*)d_in[2];
  const float* b1    = (const float*)d_in[3];
  const float* W2    = (const float*)d_in[4];
  const float* b2    = (const float*)d_in[5];
  const float* Wo1   = (const float*)d_in[6];
  const float* bo1   = (const float*)d_in[7];
  const float* Wo2   = (const float*)d_in[8];
  const float* bo2   = (const float*)d_in[9];
  const float* gamma = (const float*)d_in[10];
  const float* beta  = (const float*)d_in[11];
  float* out = (float*)d_out;

  size_t off = 0;
  auto alloc = [&](size_t bytes) -> void* {
    void* p = (char*)d_ws + off;
    off += (bytes + 255) & ~(size_t)255;
    return p;
  };
  unsigned short* xm_h   = (unsigned short*)alloc((size_t)Tt * Dd * 2);
  float*          hidden = (float*)alloc((size_t)Tt * DMm * 4);
  unsigned short* h1     = (unsigned short*)hidden;  // alias: hidden dead before h1 written
  unsigned short* W1t    = (unsigned short*)alloc((size_t)Pp * Dd * DMm * 2);
  unsigned short* W2t    = (unsigned short*)alloc((size_t)Pp * DMm * Dd * 2);
  unsigned short* Wo1t   = (unsigned short*)alloc((size_t)Dd * DMm * 2);
  int* idx      = (int*)alloc(Tt * 4);
  int* counts   = (int*)alloc(64 * 4);
  int* nflag    = counts + 16;
  int* flagged  = (int*)alloc(Tt * 4);
  int* tokenlist = (int*)alloc((size_t)Pp * Tt * 4);

  k_mix2<<<Tt, 256, 0, stream>>>(x, mk, xm_h, counts);
  k_cvt_all<<<dim3(32, 32, 2 * Pp + 1), 256, 0, stream>>>(W1, W2, Wo1, W1t, W2t, Wo1t);

  k_gemm<Dd, DMm, 0, false><<<dim3(Tt / 64, DMm / 128), 256, 0, stream>>>(
      xm_h, Wo1t, bo1, nullptr, hidden, nullptr, nullptr, nullptr);
  k_score<<<Tt / 4, 256, 0, stream>>>(hidden, Wo2, bo2, idx, nflag, flagged);
  k_rescue<<<256, 256, 0, stream>>>(x, mk, Wo1, bo1, Wo2, bo2, nflag, flagged, idx);
  k_scatter<<<Tt / 256, 256, 0, stream>>>(idx, counts, tokenlist);

  k_gemm<Dd, DMm, 1, true><<<dim3(MAXTILES, DMm / 128), 256, 0, stream>>>(
      xm_h, W1t, b1, nullptr, nullptr, h1, counts, tokenlist);
  k_gemm<DMm, Dd, 2, true><<<dim3(MAXTILES, Dd / 128), 256, 0, stream>>>(
      h1, W2t, b2, x, out, nullptr, counts, tokenlist);
  k_ln<<<Tt, 256, 0, stream>>>(out, gamma, beta);
}

// Round 7
// 146.707 us; speedup vs baseline: 1.6164x; 1.2188x over previous
//
#include <hip/hip_runtime.h>
#include <math.h>

#define Ss 2048
#define Dd 1024
#define Pp 9
#define DMm 256
#define Tt 8192
#define EPSf 1e-5f
#define BAND 6e-3f       // fp64-rescue band for argmax ties (R4-validated)

typedef __attribute__((ext_vector_type(8))) __bf16 bf16x8;
typedef __attribute__((ext_vector_type(4))) float f32x4;

#define GLOBAL_AS __attribute__((address_space(1)))
#define LDS_AS __attribute__((address_space(3)))

#define MAXTILES 137     // sum_p ceil(cnt_p/64) <= 8192/64 + 9

__device__ __forceinline__ unsigned short bf16rn(float f) {
  unsigned int u = __float_as_uint(f);
  unsigned int r = (u + 0x7fffu + ((u >> 16) & 1u)) >> 16;
  return (unsigned short)r;
}

__device__ __forceinline__ void gload16(const void* g, void* l) {
  __builtin_amdgcn_global_load_lds((const GLOBAL_AS unsigned int*)g,
                                   (LDS_AS unsigned int*)l, 16, 0, 0);
}

// swizzled LDS short-offset for logical (row r, 16B-slot sl); row = 64 shorts (128B)
#define KSW(r, sl) (((r) << 6) + ((((sl) ^ ((r) & 7))) << 3))

// ---------------------------------------------------------------- mix -> bf16 (+ zero counts)
__global__ __launch_bounds__(256) void k_mix2(const float* __restrict__ x,
    const float* __restrict__ mk, unsigned short* __restrict__ xh,
    int* __restrict__ counts) {
  if (blockIdx.x == 0 && threadIdx.x < 64) counts[threadIdx.x] = 0;
  const int t = blockIdx.x;
  const int s = t & (Ss - 1);
  const int d = threadIdx.x << 2;
  const float* xc = x + (size_t)t * Dd + d;
  float4 vb = *(const float4*)xc;
  float4 va = make_float4(0.f, 0.f, 0.f, 0.f);
  float4 vc = make_float4(0.f, 0.f, 0.f, 0.f);
  if (s > 0)      va = *(const float4*)(xc - Dd);
  if (s < Ss - 1) vc = *(const float4*)(xc + Dd);
  const float4 k0 = *(const float4*)(mk + d);
  const float4 k1 = *(const float4*)(mk + Dd + d);
  const float4 k2 = *(const float4*)(mk + 2 * Dd + d);
  float4 o;
  o.x = k0.x * va.x + k1.x * vb.x + k2.x * vc.x;
  o.y = k0.y * va.y + k1.y * vb.y + k2.y * vc.y;
  o.z = k0.z * va.z + k1.z * vb.z + k2.z * vc.z;
  o.w = k0.w * va.w + k1.w * vb.w + k2.w * vc.w;
  ushort4 h;
  h.x = bf16rn(o.x); h.y = bf16rn(o.y); h.z = bf16rn(o.z); h.w = bf16rn(o.w);
  *(ushort4*)(xh + (size_t)t * Dd + d) = h;
}

// ---------------------------------------------------------------- all weight converts, dense grid (32,8,19)
__global__ __launch_bounds__(256) void k_cvt_all(
    const float* __restrict__ W1, const float* __restrict__ W2,
    const float* __restrict__ Wo1,
    unsigned short* __restrict__ W1t, unsigned short* __restrict__ W2t,
    unsigned short* __restrict__ Wo1t) {
  const int z = blockIdx.z;
  const float* in; unsigned short* outp; int R, C, r0, c0;
  if (z < Pp)            { in = W1;  outp = W1t;  R = Dd;  C = DMm;
                           r0 = blockIdx.x * 32; c0 = blockIdx.y * 32; }
  else if (z < 2 * Pp)   { in = W2;  outp = W2t;  R = DMm; C = Dd;
                           r0 = blockIdx.y * 32; c0 = blockIdx.x * 32; }
  else                   { in = Wo1; outp = Wo1t; R = Dd;  C = DMm;
                           r0 = blockIdx.x * 32; c0 = blockIdx.y * 32; }
  const int zi = (z < Pp) ? z : ((z < 2 * Pp) ? z - Pp : 0);
  const size_t zo = (size_t)zi * R * C;
  __shared__ float tile[32][33];
  const int tr = threadIdx.x >> 3, tc = (threadIdx.x & 7) << 2;
  float4 v = *(const float4*)(in + zo + (size_t)(r0 + tr) * C + c0 + tc);
  tile[tr][tc] = v.x; tile[tr][tc + 1] = v.y; tile[tr][tc + 2] = v.z; tile[tr][tc + 3] = v.w;
  __syncthreads();
  ushort4 h;
  h.x = bf16rn(tile[tc + 0][tr]); h.y = bf16rn(tile[tc + 1][tr]);
  h.z = bf16rn(tile[tc + 2][tr]); h.w = bf16rn(tile[tc + 3][tr]);
  *(ushort4*)(outp + zo + (size_t)(c0 + tr) * R + r0 + tc) = h;
}

// ---------------------------------------------------------------- pipelined MFMA GEMM, 64x128 tile, BK=64
// Packed grid: grouped blocks self-map blockIdx.x -> (path, tile) via counts scan.
// MODE 0: outf = tanh(acc+bias)   MODE 1: outh = bf16(acc+bias)   MODE 2: outf = acc+bias+resid
template<int KTOT, int NTOT, int MODE, bool GROUPED>
__global__ __launch_bounds__(256) void k_gemm(
    const unsigned short* __restrict__ A,
    const unsigned short* __restrict__ Bt,
    const float* __restrict__ bias,
    const float* __restrict__ resid,
    float* __restrict__ outf, unsigned short* __restrict__ outh,
    const int* __restrict__ counts, const int* __restrict__ tokenlist) {
  int p = 0, ti = blockIdx.x, cnt = Tt;
  if (GROUPED) {
    for (p = 0; p < Pp; ++p) {
      cnt = counts[p];
      const int nt = (cnt + 63) >> 6;
      if (ti < nt) break;
      ti -= nt;
    }
    if (p == Pp) return;
  }
  const int tile0 = ti * 64;
  __shared__ int tl[64];
  __shared__ __align__(16) unsigned short As[2][64 * 64];   // 2 x 8 KB
  __shared__ __align__(16) unsigned short Bs[2][128 * 64];  // 2 x 16 KB
  const int tid = threadIdx.x;
  if (tid < 64) {
    const int li = tile0 + tid;
    if (GROUPED) tl[tid] = (li < cnt) ? tokenlist[p * Tt + li] : tokenlist[p * Tt];
    else         tl[tid] = li;
  }
  __syncthreads();
  const int w = tid >> 6, lane = tid & 63;
  const int fr = lane & 15, fs = lane >> 4;
  const int wr = w >> 1, wc = w & 1;
  const int n0 = blockIdx.y * 128;
  const unsigned short* Bp0 = Bt + (size_t)p * NTOT * KTOT + (size_t)n0 * KTOT;
  // staging: unit u ; global (row u>>3, slot (u&7)^(row&7)) ; LDS linear at u*16B
  const unsigned short* srcA[2];
  #pragma unroll
  for (int i = 0; i < 2; ++i) {
    const int u = i * 256 + tid, r = u >> 3, sl = (u & 7) ^ (r & 7);
    srcA[i] = A + (size_t)tl[r] * KTOT + sl * 8;
  }
  const unsigned short* srcB[4];
  #pragma unroll
  for (int i = 0; i < 4; ++i) {
    const int u = i * 256 + tid, r = u >> 3, sl = (u & 7) ^ (r & 7);
    srcB[i] = Bp0 + (size_t)r * KTOT + sl * 8;
  }
  const int ldsW = w * 512;  // wave-uniform dest offset (shorts)
  // fragment read offsets (swizzled)
  int aoff[2][2], boff[4][2];
  #pragma unroll
  for (int m = 0; m < 2; ++m)
    #pragma unroll
    for (int kk = 0; kk < 2; ++kk)
      aoff[m][kk] = KSW(wr * 32 + m * 16 + fr, kk * 4 + fs);
  #pragma unroll
  for (int n = 0; n < 4; ++n)
    #pragma unroll
    for (int kk = 0; kk < 2; ++kk)
      boff[n][kk] = KSW(wc * 64 + n * 16 + fr, kk * 4 + fs);

#define STAGE(b, kb) do { \
    gload16(srcA[0] + (kb), &As[b][0] + ldsW); \
    gload16(srcA[1] + (kb), &As[b][0] + 2048 + ldsW); \
    gload16(srcB[0] + (kb), &Bs[b][0] + ldsW); \
    gload16(srcB[1] + (kb), &Bs[b][0] + 2048 + ldsW); \
    gload16(srcB[2] + (kb), &Bs[b][0] + 4096 + ldsW); \
    gload16(srcB[3] + (kb), &Bs[b][0] + 6144 + ldsW); \
  } while (0)

  f32x4 acc[2][4] = {};
  const int NS = KTOT / 64;
  STAGE(0, 0);
  for (int s = 0; s < NS; ++s) {
    const int buf = s & 1;
    if (s + 1 < NS) {
      STAGE(buf ^ 1, (s + 1) * 64);
      asm volatile("s_waitcnt vmcnt(6)" ::: "memory");   // current buf's 6 loads done
    } else {
      asm volatile("s_waitcnt vmcnt(0)" ::: "memory");
    }
    __builtin_amdgcn_s_barrier();
    __builtin_amdgcn_sched_barrier(0);
    const unsigned short* Ab = &As[buf][0];
    const unsigned short* Bb_ = &Bs[buf][0];
    bf16x8 a[2][2], b[4][2];
    #pragma unroll
    for (int m = 0; m < 2; ++m)
      #pragma unroll
      for (int kk = 0; kk < 2; ++kk)
        a[m][kk] = *(const bf16x8*)&Ab[aoff[m][kk]];
    #pragma unroll
    for (int n = 0; n < 4; ++n)
      #pragma unroll
      for (int kk = 0; kk < 2; ++kk)
        b[n][kk] = *(const bf16x8*)&Bb_[boff[n][kk]];
    #pragma unroll
    for (int kk = 0; kk < 2; ++kk)
      #pragma unroll
      for (int m = 0; m < 2; ++m)
        #pragma unroll
        for (int n = 0; n < 4; ++n)
          acc[m][n] = __builtin_amdgcn_mfma_f32_16x16x32_bf16(a[m][kk], b[n][kk], acc[m][n], 0, 0, 0);
    __builtin_amdgcn_s_barrier();   // reads of buf done before restage
  }
#undef STAGE

  // C/D layout: col = fr, row = fs*4 + j
  const float* bias_z = bias + (size_t)p * NTOT;
  #pragma unroll
  for (int m = 0; m < 2; ++m) {
    #pragma unroll
    for (int j = 0; j < 4; ++j) {
      const int rr = wr * 32 + m * 16 + fs * 4 + j;
      const int li = tile0 + rr;
      if (GROUPED && li >= cnt) continue;
      const int t = tl[rr];
      #pragma unroll
      for (int n = 0; n < 4; ++n) {
        const int c = n0 + wc * 64 + n * 16 + fr;
        const float v = acc[m][n][j] + bias_z[c];
        if (MODE == 0)      outf[(size_t)t * NTOT + c] = tanhf(v);
        else if (MODE == 1) outh[(size_t)t * NTOT + c] = bf16rn(v);
        else                outf[(size_t)t * NTOT + c] = v + resid[(size_t)t * NTOT + c];
      }
    }
  }
}

// ---------------------------------------------------------------- scores + argmax + near-tie flag
__global__ __launch_bounds__(256) void k_score(const float* __restrict__ hidden,
    const float* __restrict__ Wo2, const float* __restrict__ bo2,
    int* __restrict__ idx, int* __restrict__ nflag, int* __restrict__ flagged) {
  __shared__ float sW[DMm * Pp];
  const int tid = threadIdx.x;
  for (int l = tid; l < DMm * Pp; l += 256) sW[l] = Wo2[l];
  __syncthreads();
  const int wave = tid >> 6, lane = tid & 63;
  const int t = blockIdx.x * 4 + wave;
  const float4 h = *(const float4*)(hidden + (size_t)t * DMm + lane * 4);
  const int m = lane * 4;
  float part[Pp];
  #pragma unroll
  for (int pp = 0; pp < Pp; ++pp)
    part[pp] = h.x * sW[(m + 0) * Pp + pp] + h.y * sW[(m + 1) * Pp + pp]
             + h.z * sW[(m + 2) * Pp + pp] + h.w * sW[(m + 3) * Pp + pp];
  #pragma unroll
  for (int off = 32; off > 0; off >>= 1)
    #pragma unroll
    for (int pp = 0; pp < Pp; ++pp)
      part[pp] += __shfl_xor(part[pp], off);
  if (lane == 0) {
    float best = -1e30f, second = -1e30f;
    int bi = 0;
    #pragma unroll
    for (int pp = 0; pp < Pp; ++pp) {
      const float sc = part[pp] + bo2[pp];
      if (sc > best) { second = best; best = sc; bi = pp; }
      else if (sc > second) second = sc;
    }
    idx[t] = bi;
    if (best - second < BAND) {
      const int pos = atomicAdd(nflag, 1);
      flagged[pos] = t;
    }
  }
}

// ---------------------------------------------------------------- fp64 rescue (parallelized)
__global__ __launch_bounds__(256) void k_rescue(const float* __restrict__ x,
    const float* __restrict__ mk,
    const float* __restrict__ Wo1, const float* __restrict__ bo1,
    const float* __restrict__ Wo2, const float* __restrict__ bo2,
    const int* __restrict__ nflag, const int* __restrict__ flagged,
    int* __restrict__ idx) {
  __shared__ double sx[Dd];
  __shared__ double th[DMm];
  __shared__ double red[4][12];
  const int nf = *nflag;
  const int tid = threadIdx.x;
  const int wv = tid >> 6, ln = tid & 63;
  for (int f = blockIdx.x; f < nf; f += gridDim.x) {
    const int t = flagged[f];
    const int s = t & (Ss - 1);
    for (int l = tid; l < Dd; l += 256) {
      const double xa = (s > 0)      ? (double)x[(size_t)(t - 1) * Dd + l] : 0.0;
      const double xb =                (double)x[(size_t)t * Dd + l];
      const double xc = (s < Ss - 1) ? (double)x[(size_t)(t + 1) * Dd + l] : 0.0;
      sx[l] = (double)mk[l] * xa + (double)mk[Dd + l] * xb + (double)mk[2 * Dd + l] * xc;
    }
    __syncthreads();
    {
      double a0 = 0, a1 = 0, a2 = 0, a3 = 0;
      const float* wcol = Wo1 + tid;
      for (int d = 0; d < Dd; d += 4) {
        a0 += sx[d + 0] * (double)wcol[(size_t)(d + 0) * DMm];
        a1 += sx[d + 1] * (double)wcol[(size_t)(d + 1) * DMm];
        a2 += sx[d + 2] * (double)wcol[(size_t)(d + 2) * DMm];
        a3 += sx[d + 3] * (double)wcol[(size_t)(d + 3) * DMm];
      }
      th[tid] = tanh(((a0 + a1) + (a2 + a3)) + (double)bo1[tid]);
    }
    __syncthreads();
    double pr[Pp];
    const double tv = th[tid];
    #pragma unroll
    for (int p = 0; p < Pp; ++p) pr[p] = tv * (double)Wo2[tid * Pp + p];
    #pragma unroll
    for (int off = 32; off > 0; off >>= 1)
      #pragma unroll
      for (int p = 0; p < Pp; ++p) pr[p] += __shfl_xor(pr[p], off);
    if (ln == 0) {
      #pragma unroll
      for (int p = 0; p < Pp; ++p) red[wv][p] = pr[p];
    }
    __syncthreads();
    if (tid == 0) {
      double best = -1e300; int bi = 0;
      #pragma unroll
      for (int p = 0; p < Pp; ++p) {
        const double sv = red[0][p] + red[1][p] + red[2][p] + red[3][p] + (double)bo2[p];
        if (sv > best) { best = sv; bi = p; }
      }
      idx[t] = bi;
    }
    __syncthreads();
  }
}

// ---------------------------------------------------------------- group tokens by path (LDS histogram)
__global__ __launch_bounds__(256) void k_scatter(const int* __restrict__ idx,
    int* __restrict__ counts, int* __restrict__ tokenlist) {
  __shared__ int lcnt[Pp], lbase[Pp];
  const int tid = threadIdx.x;
  if (tid < Pp) lcnt[tid] = 0;
  __syncthreads();
  const int t = blockIdx.x * 256 + tid;
  const int p = idx[t];
  const int slot = atomicAdd(&lcnt[p], 1);     // LDS atomic: cheap
  __syncthreads();
  if (tid < Pp) lbase[tid] = atomicAdd(&counts[tid], lcnt[tid]);  // 9 global atomics/block
  __syncthreads();
  tokenlist[p * Tt + lbase[p] + slot] = t;
}

// ---------------------------------------------------------------- in-place LayerNorm
__global__ __launch_bounds__(256) void k_ln(float* __restrict__ y,
    const float* __restrict__ gamma, const float* __restrict__ beta) {
  const int t = blockIdx.x;
  const int d = threadIdx.x << 2;
  float* row = y + (size_t)t * Dd;
  float4 v = *(float4*)(row + d);
  float s = v.x + v.y + v.z + v.w;
  float q = v.x * v.x + v.y * v.y + v.z * v.z + v.w * v.w;
  #pragma unroll
  for (int off = 32; off > 0; off >>= 1) {
    s += __shfl_xor(s, off);
    q += __shfl_xor(q, off);
  }
  __shared__ float ssum[4], sqq[4];
  const int wave = threadIdx.x >> 6, lane = threadIdx.x & 63;
  if (lane == 0) { ssum[wave] = s; sqq[wave] = q; }
  __syncthreads();
  s = ssum[0] + ssum[1] + ssum[2] + ssum[3];
  q = sqq[0] + sqq[1] + sqq[2] + sqq[3];
  const float mu = s * (1.f / Dd);
  const float var = q * (1.f / Dd) - mu * mu;
  const float inv = rsqrtf(var + EPSf);
  const float4 g = *(const float4*)(gamma + d);
  const float4 bt = *(const float4*)(beta + d);
  float4 o;
  o.x = (v.x - mu) * inv * g.x + bt.x;
  o.y = (v.y - mu) * inv * g.y + bt.y;
  o.z = (v.z - mu) * inv * g.z + bt.z;
  o.w = (v.w - mu) * inv * g.w + bt.w;
  *(float4*)(row + d) = o;
}

// ----------------------------------------------------------------
extern "C" void kernel_launch(void* const* d_in, const int* in_sizes, int n_in,
                              void* d_out, int out_size, void* d_ws, size_t ws_size,
                              hipStream_t stream) {
  (void)in_sizes; (void)n_in; (void)out_size; (void)ws_size;
  const float* x     = (const float*)d_in[0];
  const float* mk    = (const float*)d_in[1];
  const float* W1    = (const float*)d_in[2];
  const float* b1    = (const float*)d_in[3];
  const float* W2    = (const float*)d_in[4];
  const float* b2    = (const float*)d_in[5];
  const float* Wo1   = (const float*)d_in[6];
  const float* bo1   = (const float*)d_in[7];
  const float* Wo2   = (const float*)d_in[8];
  const float* bo2   = (const float*)d_in[9];
  const float* gamma = (const float*)d_in[10];
  const float* beta  = (const float*)d_in[11];
  float* out = (float*)d_out;

  size_t off = 0;
  auto alloc = [&](size_t bytes) -> void* {
    void* p = (char*)d_ws + off;
    off += (bytes + 255) & ~(size_t)255;
    return p;
  };
  unsigned short* xm_h   = (unsigned short*)alloc((size_t)Tt * Dd * 2);
  float*          hidden = (float*)alloc((size_t)Tt * DMm * 4);
  unsigned short* h1     = (unsigned short*)hidden;  // alias: hidden dead before h1 written
  unsigned short* W1t    = (unsigned short*)alloc((size_t)Pp * Dd * DMm * 2);
  unsigned short* W2t    = (unsigned short*)alloc((size_t)Pp * DMm * Dd * 2);
  unsigned short* Wo1t   = (unsigned short*)alloc((size_t)Dd * DMm * 2);
  int* idx      = (int*)alloc(Tt * 4);
  int* counts   = (int*)alloc(64 * 4);
  int* nflag    = counts + 16;
  int* flagged  = (int*)alloc(Tt * 4);
  int* tokenlist = (int*)alloc((size_t)Pp * Tt * 4);

  k_mix2<<<Tt, 256, 0, stream>>>(x, mk, xm_h, counts);
  k_cvt_all<<<dim3(32, 8, 2 * Pp + 1), 256, 0, stream>>>(W1, W2, Wo1, W1t, W2t, Wo1t);

  k_gemm<Dd, DMm, 0, false><<<dim3(Tt / 64, DMm / 128), 256, 0, stream>>>(
      xm_h, Wo1t, bo1, nullptr, hidden, nullptr, nullptr, nullptr);
  k_score<<<Tt / 4, 256, 0, stream>>>(hidden, Wo2, bo2, idx, nflag, flagged);
  k_rescue<<<256, 256, 0, stream>>>(x, mk, Wo1, bo1, Wo2, bo2, nflag, flagged, idx);
  k_scatter<<<Tt / 256, 256, 0, stream>>>(idx, counts, tokenlist);

  k_gemm<Dd, DMm, 1, true><<<dim3(MAXTILES, DMm / 128), 256, 0, stream>>>(
      xm_h, W1t, b1, nullptr, nullptr, h1, counts, tokenlist);
  k_gemm<DMm, Dd, 2, true><<<dim3(MAXTILES, Dd / 128), 256, 0, stream>>>(
      h1, W2t, b2, x, out, nullptr, counts, tokenlist);
  k_ln<<<Tt, 256, 0, stream>>>(out, gamma, beta);
}